// Round 12
// baseline (455.417 us; speedup 1.0000x reference)
//
#include <hip/hip_runtime.h>
#include <hip/hip_bf16.h>

#define NN 50000
#define EE 250000
#define HH 128
#define EPS_ 1e-5f
#define SCB 196  // scan segments per relation: ceil(NN/256)

typedef __attribute__((ext_vector_type(8))) short bf16x8;
typedef __attribute__((ext_vector_type(4))) float f32x4;

__device__ __forceinline__ float bf2f(ushort u) {
  union { unsigned int i; float f; } x; x.i = ((unsigned int)u) << 16; return x.f;
}
__device__ __forceinline__ ushort f2bf(float f) {
  union { float f; unsigned int i; } x; x.f = f;
  unsigned int r = (x.i + 0x7fffu + ((x.i >> 16) & 1u)) >> 16;  // RNE, finite inputs
  return (ushort)r;
}

// st float layout:
// 0:sum0 128:sq0 256:sum1 384:sq1 | 512:scale0 640:shift0 768:scale1 896:shift1
// 1024:W2p0[256] 1280:W2p1[256] 1536:b2p0[2] 1538:b2p1[2]

// ---------------- degree / CSR build ----------------
__global__ void k_count(const int* __restrict__ bei, const int* __restrict__ cei,
                        int* __restrict__ cntb, int* __restrict__ cntc) {
  int i = blockIdx.x * blockDim.x + threadIdx.x;
  if (i < EE) atomicAdd(&cntb[bei[EE + i]], 1);
  else if (i < 2 * EE) atomicAdd(&cntc[cei[EE + (i - EE)]], 1);
}

__global__ void k_dinv(const int* __restrict__ cnt, float* __restrict__ dinv) {
  int i = blockIdx.x * blockDim.x + threadIdx.x;  // 2N
  if (i < 2 * NN) dinv[i] = rsqrtf((float)cnt[i] + 1.0f);
}

__global__ void k_scan_part(const int* __restrict__ cnt, int* __restrict__ part) {
  int rel = blockIdx.x / SCB, b = blockIdx.x % SCB;
  int n = b * 256 + threadIdx.x;
  int v = (n < NN) ? cnt[rel * NN + n] : 0;
#pragma unroll
  for (int m = 32; m >= 1; m >>= 1) v += __shfl_xor(v, m, 64);
  __shared__ int red[4];
  if ((threadIdx.x & 63) == 0) red[threadIdx.x >> 6] = v;
  __syncthreads();
  if (threadIdx.x == 0) part[rel * SCB + b] = red[0] + red[1] + red[2] + red[3];
}

__global__ void k_scan_base(int* __restrict__ part) {
  __shared__ int s[256];
  int t = threadIdx.x;
  for (int rel = 0; rel < 2; ++rel) {
    int v = (t < SCB) ? part[rel * SCB + t] : 0;
    s[t] = v;
    __syncthreads();
    for (int ofs = 1; ofs < 256; ofs <<= 1) {
      int x = (t >= ofs) ? s[t - ofs] : 0;
      __syncthreads();
      s[t] += x;
      __syncthreads();
    }
    if (t < SCB) part[rel * SCB + t] = s[t] - v;  // exclusive
    __syncthreads();
  }
}

__global__ void k_scan_off(const int* __restrict__ cnt, const int* __restrict__ part,
                           int* __restrict__ off, int* __restrict__ cur) {
  int rel = blockIdx.x / SCB, b = blockIdx.x % SCB;
  int t = threadIdx.x;
  int n = b * 256 + t;
  int v = (n < NN) ? cnt[rel * NN + n] : 0;
  __shared__ int s[256];
  s[t] = v;
  __syncthreads();
  for (int ofs = 1; ofs < 256; ofs <<= 1) {
    int x = (t >= ofs) ? s[t - ofs] : 0;
    __syncthreads();
    s[t] += x;
    __syncthreads();
  }
  if (n < NN) {
    int o = part[rel * SCB + b] + s[t] - v;
    off[rel * NN + n] = o;
    cur[rel * NN + n] = o;
  }
}

__global__ void k_fill(const int* __restrict__ bei, const int* __restrict__ cei,
                       int* __restrict__ curb, int* __restrict__ listb,
                       int* __restrict__ dlistb, int* __restrict__ elistb,
                       int* __restrict__ curc, int* __restrict__ listc,
                       int* __restrict__ dlistc, int* __restrict__ elistc) {
  int i = blockIdx.x * blockDim.x + threadIdx.x;
  if (i < EE) {
    int dst = bei[EE + i];
    int p = atomicAdd(&curb[dst], 1);
    listb[p] = bei[i];
    dlistb[p] = dst;
    elistb[p] = i;
  } else if (i < 2 * EE) {
    int e = i - EE;
    int dst = cei[EE + e];
    int p = atomicAdd(&curc[dst], 1);
    listc[p] = cei[e];
    dlistc[p] = dst;
    elistc[p] = e;
  }
}

// ---------------- encoder: relu(x@W_enc+b) -> bf16 (pre-BN), accumulate BN stats ----------------
__global__ void k_encoder_bf(const float* __restrict__ x, const float* __restrict__ W,
                             const float* __restrict__ b, ushort* __restrict__ hb,
                             float* __restrict__ sum, float* __restrict__ sumsq) {
  int t = threadIdx.x;
  int c = t & 127, r = t >> 7;
  int n0 = blockIdx.x * 64;
  float w0 = W[c], w1 = W[HH + c], w2 = W[2 * HH + c], bb = b[c];
  float ls = 0.f, lss = 0.f;
  for (int rr = r; rr < 64; rr += 2) {
    int n = n0 + rr;
    if (n < NN) {
      float v = fmaxf(x[n * 3] * w0 + x[n * 3 + 1] * w1 + x[n * 3 + 2] * w2 + bb, 0.f);
      ushort u = f2bf(v);
      hb[(size_t)n * HH + c] = u;
      float vr = bf2f(u);
      ls += vr; lss += vr * vr;
    }
  }
  __shared__ float red[2][HH];
  red[r][c] = ls; __syncthreads();
  if (r == 0) atomicAdd(&sum[c], red[0][c] + red[1][c]);
  __syncthreads();
  red[r][c] = lss; __syncthreads();
  if (r == 0) atomicAdd(&sumsq[c], red[0][c] + red[1][c]);
}

__global__ void k_bn_finalize(const float* __restrict__ sum, const float* __restrict__ sumsq,
                              const float* __restrict__ g, const float* __restrict__ be,
                              float* __restrict__ scale, float* __restrict__ shift, float invn) {
  int c = threadIdx.x;
  float m = sum[c] * invn;
  float v = fmaxf(sumsq[c] * invn - m * m, 0.f);
  float s = g[c] * rsqrtf(v + EPS_);
  scale[c] = s;
  shift[c] = be[c] - m * s;
}

// 2-relation finalize + BN-folded W2 (W2p = scale*W2, b2p = b2 + shift@W2)
__global__ void k_bn_finalize3(float* __restrict__ st, const float* __restrict__ g0,
                               const float* __restrict__ be0, const float* __restrict__ g1,
                               const float* __restrict__ be1,
                               const float* __restrict__ W2_0, const float* __restrict__ b2_0,
                               const float* __restrict__ W2_1, const float* __restrict__ b2_1,
                               float invn) {
  int t = threadIdx.x;  // 256
  int rel = t >> 7, c = t & 127;
  const float* sum = st + rel * 2 * HH;
  const float* sq  = sum + HH;
  float* scale = st + 512 + rel * 256;
  float* shift = scale + HH;
  const float* g = rel ? g1 : g0;
  const float* be = rel ? be1 : be0;
  const float* W2 = rel ? W2_1 : W2_0;
  float m = sum[c] * invn;
  float v = fmaxf(sq[c] * invn - m * m, 0.f);
  float sc = g[c] * rsqrtf(v + EPS_);
  float sh = be[c] - m * sc;
  scale[c] = sc;
  shift[c] = sh;
  float w20 = W2[c * 2], w21 = W2[c * 2 + 1];
  st[1024 + rel * 256 + c * 2 + 0] = sc * w20;
  st[1024 + rel * 256 + c * 2 + 1] = sc * w21;
  __shared__ float red[2][HH][2];
  red[rel][c][0] = sh * w20;
  red[rel][c][1] = sh * w21;
  __syncthreads();
  if (c < 2) {
    float s = 0.f;
    for (int i = 0; i < HH; ++i) s += red[rel][i][c];
    st[1536 + rel * 2 + c] = (rel ? b2_1 : b2_0)[c] + s;
  }
}

// ---------------- weight transposes to bf16 (merged) ----------------
__global__ void k_wt_all(const float* __restrict__ s0, const float* __restrict__ s1,
                         const float* __restrict__ s2, const float* __restrict__ s3,
                         ushort* __restrict__ d0, ushort* __restrict__ d1,
                         ushort* __restrict__ d2, ushort* __restrict__ d3,
                         const float* __restrict__ m0, const float* __restrict__ m1,
                         ushort* __restrict__ e0, ushort* __restrict__ e1) {
  int i = blockIdx.x * 256 + threadIdx.x;
  if (i < 4 * 16384) {
    int sel = i >> 14, loc = i & 16383;
    int k = loc >> 7, c = loc & 127;
    const float* s = sel == 0 ? s0 : sel == 1 ? s1 : sel == 2 ? s2 : s3;
    ushort* d = sel == 0 ? d0 : sel == 1 ? d1 : sel == 2 ? d2 : d3;
    d[c * 128 + k] = f2bf(s[loc]);
  } else if (i < 4 * 16384 + 2 * 32768) {
    int j = i - 4 * 16384;
    int sel = j >> 15, loc = j & 32767;
    int k = loc >> 7, c = loc & 127;
    const float* s = sel ? m1 : m0;
    ushort* d = sel ? e1 : e0;
    d[c * 256 + k] = f2bf(s[loc]);
  }
}

// ---------------- bf16 GEMM pair (optional fused BN on A-read) ----------------
template <int APPLYBN>
__global__ __launch_bounds__(256) void k_gemm_bf2(const ushort* __restrict__ X,
                                                  const ushort* __restrict__ Wt0,
                                                  ushort* __restrict__ Y0,
                                                  const ushort* __restrict__ Wt1,
                                                  ushort* __restrict__ Y1,
                                                  const float* __restrict__ bnsc,
                                                  const float* __restrict__ bnsh) {
  const int nb = gridDim.x >> 1;
  const int rel = blockIdx.x >= nb;
  const int blk = rel ? blockIdx.x - nb : blockIdx.x;
  const ushort* Wt = rel ? Wt1 : Wt0;
  ushort* Y = rel ? Y1 : Y0;
  const int t = threadIdx.x;
  const int l = t & 63, wid = t >> 6;
  const int wm = wid >> 1, wn = wid & 1;
  const int lr = l & 15, lg = l >> 4;
  const int n0 = blk * 64;
  f32x4 acc[2][4];
#pragma unroll
  for (int mf = 0; mf < 2; ++mf)
#pragma unroll
    for (int nf = 0; nf < 4; ++nf) acc[mf][nf] = (f32x4){0.f, 0.f, 0.f, 0.f};
  int r0 = n0 + wm * 32 + lr;
  int rA = min(r0, NN - 1), rB = min(r0 + 16, NN - 1);
  const ushort* xa = X + (size_t)rA * HH + lg * 8;
  const ushort* xb = X + (size_t)rB * HH + lg * 8;
#pragma unroll
  for (int ks = 0; ks < 4; ++ks) {
    bf16x8 a0 = *(const bf16x8*)(xa + ks * 32);
    bf16x8 a1 = *(const bf16x8*)(xb + ks * 32);
    if (APPLYBN) {
      int k0 = ks * 32 + lg * 8;
#pragma unroll
      for (int i = 0; i < 8; ++i) {
        float sc = bnsc[k0 + i], sh = bnsh[k0 + i];
        a0[i] = (short)f2bf(bf2f((ushort)a0[i]) * sc + sh);
        a1[i] = (short)f2bf(bf2f((ushort)a1[i]) * sc + sh);
      }
    }
#pragma unroll
    for (int nf = 0; nf < 4; ++nf) {
      int col = wn * 64 + nf * 16 + lr;
      bf16x8 b = *(const bf16x8*)(Wt + col * 128 + ks * 32 + lg * 8);
      acc[0][nf] = __builtin_amdgcn_mfma_f32_16x16x32_bf16(a0, b, acc[0][nf], 0, 0, 0);
      acc[1][nf] = __builtin_amdgcn_mfma_f32_16x16x32_bf16(a1, b, acc[1][nf], 0, 0, 0);
    }
  }
#pragma unroll
  for (int mf = 0; mf < 2; ++mf)
#pragma unroll
    for (int nf = 0; nf < 4; ++nf) {
      int col = wn * 64 + nf * 16 + lr;
#pragma unroll
      for (int j = 0; j < 4; ++j) {
        int row = n0 + wm * 32 + mf * 16 + lg * 4 + j;
        if (row < NN) Y[(size_t)row * HH + col] = f2bf(acc[mf][nf][j]);
      }
    }
}

// ---------------- UV GEMMs: U=h2@W1_top, V=h2@W1_bot per relation ----------------
__global__ __launch_bounds__(256) void k_gemm_uv(const ushort* __restrict__ X,
                                                 const ushort* __restrict__ Wm0,
                                                 const ushort* __restrict__ Wm1,
                                                 ushort* __restrict__ U0, ushort* __restrict__ V0,
                                                 ushort* __restrict__ U1, ushort* __restrict__ V1) {
  const int nb = gridDim.x >> 2;
  const int sel = blockIdx.x / nb;
  const int blk = blockIdx.x - sel * nb;
  const ushort* Wm = (sel >> 1) ? Wm1 : Wm0;
  const int koff = (sel & 1) * 128;
  ushort* Y = sel == 0 ? U0 : sel == 1 ? V0 : sel == 2 ? U1 : V1;
  const int t = threadIdx.x;
  const int l = t & 63, wid = t >> 6;
  const int wm = wid >> 1, wn = wid & 1;
  const int lr = l & 15, lg = l >> 4;
  const int n0 = blk * 64;
  f32x4 acc[2][4];
#pragma unroll
  for (int mf = 0; mf < 2; ++mf)
#pragma unroll
    for (int nf = 0; nf < 4; ++nf) acc[mf][nf] = (f32x4){0.f, 0.f, 0.f, 0.f};
  int r0 = n0 + wm * 32 + lr;
  int rA = min(r0, NN - 1), rB = min(r0 + 16, NN - 1);
  const ushort* xa = X + (size_t)rA * HH + lg * 8;
  const ushort* xb = X + (size_t)rB * HH + lg * 8;
#pragma unroll
  for (int ks = 0; ks < 4; ++ks) {
    bf16x8 a0 = *(const bf16x8*)(xa + ks * 32);
    bf16x8 a1 = *(const bf16x8*)(xb + ks * 32);
#pragma unroll
    for (int nf = 0; nf < 4; ++nf) {
      int col = wn * 64 + nf * 16 + lr;
      bf16x8 b = *(const bf16x8*)(Wm + col * 256 + koff + ks * 32 + lg * 8);
      acc[0][nf] = __builtin_amdgcn_mfma_f32_16x16x32_bf16(a0, b, acc[0][nf], 0, 0, 0);
      acc[1][nf] = __builtin_amdgcn_mfma_f32_16x16x32_bf16(a1, b, acc[1][nf], 0, 0, 0);
    }
  }
#pragma unroll
  for (int mf = 0; mf < 2; ++mf)
#pragma unroll
    for (int nf = 0; nf < 4; ++nf) {
      int col = wn * 64 + nf * 16 + lr;
#pragma unroll
      for (int j = 0; j < 4; ++j) {
        int row = n0 + wm * 32 + mf * 16 + lg * 4 + j;
        if (row < NN) Y[(size_t)row * HH + col] = f2bf(acc[mf][nf][j]);
      }
    }
}

// ---------------- fused aggregation v2: 16 nodes/block, 16 lanes x 8 cols, unroll-4 ----------------
template <int RELU>
__global__ __launch_bounds__(256) void k_agg2(
    const ushort* __restrict__ xwb, const ushort* __restrict__ xwc,
    const float* __restrict__ dinvb, const float* __restrict__ dinvc,
    const int* __restrict__ offb, const int* __restrict__ cntb,
    const int* __restrict__ listb,
    const int* __restrict__ offc, const int* __restrict__ cntc,
    const int* __restrict__ listc,
    const float* __restrict__ bb, const float* __restrict__ bc,
    ushort* __restrict__ out) {
  const int t = threadIdx.x;
  const int ln = t & 15;            // lane-within-node: cols ln*8 .. +7
  const int n = blockIdx.x * 16 + (t >> 4);
  if (n >= NN) return;
  const int c0 = ln * 8;
  float dnb = dinvb[n], dnc = dinvc[n];
  bf16x8 sb = *(const bf16x8*)(xwb + (size_t)n * HH + c0);
  bf16x8 sc = *(const bf16x8*)(xwc + (size_t)n * HH + c0);
  float acc[8];
#pragma unroll
  for (int i = 0; i < 8; ++i)
    acc[i] = bb[c0 + i] + bc[c0 + i] + dnb * dnb * bf2f((ushort)sb[i])
                                     + dnc * dnc * bf2f((ushort)sc[i]);
  // ---- relation b ----
  {
    int o = offb[n], e = o + cntb[n];
    float s[8];
#pragma unroll
    for (int i = 0; i < 8; ++i) s[i] = 0.f;
    for (; o + 4 <= e; o += 4) {
      int i0 = listb[o], i1 = listb[o + 1], i2 = listb[o + 2], i3 = listb[o + 3];
      float w0 = dinvb[i0], w1 = dinvb[i1], w2 = dinvb[i2], w3 = dinvb[i3];
      bf16x8 r0 = *(const bf16x8*)(xwb + (size_t)i0 * HH + c0);
      bf16x8 r1 = *(const bf16x8*)(xwb + (size_t)i1 * HH + c0);
      bf16x8 r2 = *(const bf16x8*)(xwb + (size_t)i2 * HH + c0);
      bf16x8 r3 = *(const bf16x8*)(xwb + (size_t)i3 * HH + c0);
#pragma unroll
      for (int i = 0; i < 8; ++i)
        s[i] += w0 * bf2f((ushort)r0[i]) + w1 * bf2f((ushort)r1[i])
              + w2 * bf2f((ushort)r2[i]) + w3 * bf2f((ushort)r3[i]);
    }
    for (; o < e; ++o) {
      int src = listb[o];
      float w = dinvb[src];
      bf16x8 r = *(const bf16x8*)(xwb + (size_t)src * HH + c0);
#pragma unroll
      for (int i = 0; i < 8; ++i) s[i] += w * bf2f((ushort)r[i]);
    }
#pragma unroll
    for (int i = 0; i < 8; ++i) acc[i] += dnb * s[i];
  }
  // ---- relation c ----
  {
    int o = offc[n], e = o + cntc[n];
    float s[8];
#pragma unroll
    for (int i = 0; i < 8; ++i) s[i] = 0.f;
    for (; o + 4 <= e; o += 4) {
      int i0 = listc[o], i1 = listc[o + 1], i2 = listc[o + 2], i3 = listc[o + 3];
      float w0 = dinvc[i0], w1 = dinvc[i1], w2 = dinvc[i2], w3 = dinvc[i3];
      bf16x8 r0 = *(const bf16x8*)(xwc + (size_t)i0 * HH + c0);
      bf16x8 r1 = *(const bf16x8*)(xwc + (size_t)i1 * HH + c0);
      bf16x8 r2 = *(const bf16x8*)(xwc + (size_t)i2 * HH + c0);
      bf16x8 r3 = *(const bf16x8*)(xwc + (size_t)i3 * HH + c0);
#pragma unroll
      for (int i = 0; i < 8; ++i)
        s[i] += w0 * bf2f((ushort)r0[i]) + w1 * bf2f((ushort)r1[i])
              + w2 * bf2f((ushort)r2[i]) + w3 * bf2f((ushort)r3[i]);
    }
    for (; o < e; ++o) {
      int src = listc[o];
      float w = dinvc[src];
      bf16x8 r = *(const bf16x8*)(xwc + (size_t)src * HH + c0);
#pragma unroll
      for (int i = 0; i < 8; ++i) s[i] += w * bf2f((ushort)r[i]);
    }
#pragma unroll
    for (int i = 0; i < 8; ++i) acc[i] += dnc * s[i];
  }
  bf16x8 ov;
#pragma unroll
  for (int i = 0; i < 8; ++i) {
    float v = RELU ? fmaxf(acc[i], 0.f) : acc[i];
    ov[i] = (short)f2bf(v);
  }
  *(bf16x8*)(out + (size_t)n * HH + c0) = ov;
}

// ---------------- edge pass 1 (node-centric): stats of relu(U[s]+V[d]+b1) ----------------
// Block = 16 dst-nodes x 16 lanes x 8 cols. V[d]+b1 held in registers; src edges
// gathered from CSR with unroll-4.
__global__ __launch_bounds__(256) void k_edge_pass1n(
    const ushort* __restrict__ U0, const ushort* __restrict__ V0,
    const ushort* __restrict__ U1, const ushort* __restrict__ V1,
    const int* __restrict__ off0, const int* __restrict__ cnt0, const int* __restrict__ sl0,
    const int* __restrict__ off1, const int* __restrict__ cnt1, const int* __restrict__ sl1,
    const float* __restrict__ b1_0, const float* __restrict__ b1_1,
    float* __restrict__ st) {
  const int nbk = gridDim.x >> 1;
  const int rel = blockIdx.x >= nbk;
  const int blk = rel ? blockIdx.x - nbk : blockIdx.x;
  const ushort* U = rel ? U1 : U0;
  const ushort* V = rel ? V1 : V0;
  const int* off = rel ? off1 : off0;
  const int* cnt = rel ? cnt1 : cnt0;
  const int* sl = rel ? sl1 : sl0;
  const float* b1 = rel ? b1_1 : b1_0;

  __shared__ float b1s[HH], redA[HH], redB[HH];
  const int t = threadIdx.x;
  if (t < HH) { b1s[t] = b1[t]; redA[t] = 0.f; redB[t] = 0.f; }
  __syncthreads();
  const int ln = t & 15;
  const int c0 = ln * 8;
  const int n = blk * 16 + (t >> 4);

  float ls[8], lss[8];
#pragma unroll
  for (int i = 0; i < 8; ++i) { ls[i] = 0.f; lss[i] = 0.f; }

  if (n < NN) {
    bf16x8 v = *(const bf16x8*)(V + (size_t)n * HH + c0);
    float w[8];
#pragma unroll
    for (int i = 0; i < 8; ++i) w[i] = bf2f((ushort)v[i]) + b1s[c0 + i];
    int o = off[n], e = o + cnt[n];
    for (; o + 4 <= e; o += 4) {
      int i0 = sl[o], i1 = sl[o + 1], i2 = sl[o + 2], i3 = sl[o + 3];
      bf16x8 u0 = *(const bf16x8*)(U + (size_t)i0 * HH + c0);
      bf16x8 u1 = *(const bf16x8*)(U + (size_t)i1 * HH + c0);
      bf16x8 u2 = *(const bf16x8*)(U + (size_t)i2 * HH + c0);
      bf16x8 u3 = *(const bf16x8*)(U + (size_t)i3 * HH + c0);
#pragma unroll
      for (int i = 0; i < 8; ++i) {
        float r0 = fmaxf(bf2f((ushort)u0[i]) + w[i], 0.f);
        float r1 = fmaxf(bf2f((ushort)u1[i]) + w[i], 0.f);
        float r2 = fmaxf(bf2f((ushort)u2[i]) + w[i], 0.f);
        float r3 = fmaxf(bf2f((ushort)u3[i]) + w[i], 0.f);
        ls[i] += (r0 + r1) + (r2 + r3);
        lss[i] += (r0 * r0 + r1 * r1) + (r2 * r2 + r3 * r3);
      }
    }
    for (; o < e; ++o) {
      int src = sl[o];
      bf16x8 u = *(const bf16x8*)(U + (size_t)src * HH + c0);
#pragma unroll
      for (int i = 0; i < 8; ++i) {
        float r = fmaxf(bf2f((ushort)u[i]) + w[i], 0.f);
        ls[i] += r; lss[i] += r * r;
      }
    }
  }
  // reduce across the 4 node-groups within each wave (lane bits 4,5)
#pragma unroll
  for (int m = 16; m <= 32; m <<= 1)
#pragma unroll
    for (int i = 0; i < 8; ++i) {
      ls[i] += __shfl_xor(ls[i], m, 64);
      lss[i] += __shfl_xor(lss[i], m, 64);
    }
  if ((t & 63) < 16) {
#pragma unroll
    for (int i = 0; i < 8; ++i) {
      atomicAdd(&redA[c0 + i], ls[i]);
      atomicAdd(&redB[c0 + i], lss[i]);
    }
  }
  __syncthreads();
  if (t < HH) {
    atomicAdd(&st[rel * 2 * HH + t], redA[t]);
    atomicAdd(&st[rel * 2 * HH + HH + t], redB[t]);
  }
}

// ---------------- edge pass 2 (node-centric): out[eid] = relu(U[s]+V[d]+b1) @ W2p + b2p ----------------
__global__ __launch_bounds__(256) void k_edge_pass2n(
    const ushort* __restrict__ U0, const ushort* __restrict__ V0,
    const ushort* __restrict__ U1, const ushort* __restrict__ V1,
    const int* __restrict__ off0, const int* __restrict__ cnt0,
    const int* __restrict__ sl0, const int* __restrict__ el0,
    const int* __restrict__ off1, const int* __restrict__ cnt1,
    const int* __restrict__ sl1, const int* __restrict__ el1,
    const float* __restrict__ b1_0, const float* __restrict__ b1_1,
    const float* __restrict__ st, float* __restrict__ out) {
  const int nbk = gridDim.x >> 1;
  const int rel = blockIdx.x >= nbk;
  const int blk = rel ? blockIdx.x - nbk : blockIdx.x;
  const ushort* U = rel ? U1 : U0;
  const ushort* V = rel ? V1 : V0;
  const int* off = rel ? off1 : off0;
  const int* cnt = rel ? cnt1 : cnt0;
  const int* sl = rel ? sl1 : sl0;
  const int* el = rel ? el1 : el0;
  const float* b1 = rel ? b1_1 : b1_0;
  float* o_ = out + (size_t)rel * 2 * EE;

  __shared__ float b1s[HH], w2s[256], b2s[2];
  const int t = threadIdx.x;
  if (t < HH) b1s[t] = b1[t];
  w2s[t] = st[1024 + rel * 256 + t];
  if (t < 2) b2s[t] = st[1536 + rel * 2 + t];
  __syncthreads();
  const int ln = t & 15;
  const int c0 = ln * 8;
  const int n = blk * 16 + (t >> 4);
  if (n >= NN) return;

  bf16x8 v = *(const bf16x8*)(V + (size_t)n * HH + c0);
  float w[8], wa[8], wb[8];
#pragma unroll
  for (int i = 0; i < 8; ++i) {
    w[i] = bf2f((ushort)v[i]) + b1s[c0 + i];
    wa[i] = w2s[(c0 + i) * 2];
    wb[i] = w2s[(c0 + i) * 2 + 1];
  }
  float b20 = b2s[0], b21 = b2s[1];

  int o = off[n], e = o + cnt[n];
  for (; o + 2 <= e; o += 2) {
    int i0 = sl[o], i1 = sl[o + 1];
    int e0 = el[o], e1 = el[o + 1];
    bf16x8 u0 = *(const bf16x8*)(U + (size_t)i0 * HH + c0);
    bf16x8 u1 = *(const bf16x8*)(U + (size_t)i1 * HH + c0);
    float p00 = 0.f, p01 = 0.f, p10 = 0.f, p11 = 0.f;
#pragma unroll
    for (int i = 0; i < 8; ++i) {
      float r0 = fmaxf(bf2f((ushort)u0[i]) + w[i], 0.f);
      p00 += r0 * wa[i]; p01 += r0 * wb[i];
      float r1 = fmaxf(bf2f((ushort)u1[i]) + w[i], 0.f);
      p10 += r1 * wa[i]; p11 += r1 * wb[i];
    }
#pragma unroll
    for (int m = 8; m >= 1; m >>= 1) {
      p00 += __shfl_xor(p00, m, 64); p01 += __shfl_xor(p01, m, 64);
      p10 += __shfl_xor(p10, m, 64); p11 += __shfl_xor(p11, m, 64);
    }
    if (ln == 0) {
      o_[(size_t)e0 * 2 + 0] = p00 + b20;
      o_[(size_t)e0 * 2 + 1] = p01 + b21;
      o_[(size_t)e1 * 2 + 0] = p10 + b20;
      o_[(size_t)e1 * 2 + 1] = p11 + b21;
    }
  }
  if (o < e) {
    int i0 = sl[o], e0 = el[o];
    bf16x8 u0 = *(const bf16x8*)(U + (size_t)i0 * HH + c0);
    float p00 = 0.f, p01 = 0.f;
#pragma unroll
    for (int i = 0; i < 8; ++i) {
      float r0 = fmaxf(bf2f((ushort)u0[i]) + w[i], 0.f);
      p00 += r0 * wa[i]; p01 += r0 * wb[i];
    }
#pragma unroll
    for (int m = 8; m >= 1; m >>= 1) {
      p00 += __shfl_xor(p00, m, 64); p01 += __shfl_xor(p01, m, 64);
    }
    if (ln == 0) {
      o_[(size_t)e0 * 2 + 0] = p00 + b20;
      o_[(size_t)e0 * 2 + 1] = p01 + b21;
    }
  }
}

// ---------------- edge types ----------------
__global__ void k_edge_types(float* __restrict__ out) {
  int i = blockIdx.x * 256 + threadIdx.x;
  if (i < 2 * EE) out[(size_t)2 * EE * 2 + i] = (i < EE) ? 0.0f : 1.0f;
}

extern "C" void kernel_launch(void* const* d_in, const int* in_sizes, int n_in,
                              void* d_out, int out_size, void* d_ws, size_t ws_size,
                              hipStream_t stream) {
  const float* x      = (const float*)d_in[0];
  const int*   bei    = (const int*)d_in[1];
  const int*   cei    = (const int*)d_in[2];
  const float* W_enc  = (const float*)d_in[3];
  const float* b_enc  = (const float*)d_in[4];
  const float* g_enc  = (const float*)d_in[5];
  const float* be_enc = (const float*)d_in[6];
  const float* W1b = (const float*)d_in[7];  const float* b1b = (const float*)d_in[8];
  const float* W1c = (const float*)d_in[9];  const float* b1c = (const float*)d_in[10];
  const float* W2b = (const float*)d_in[11]; const float* b2b = (const float*)d_in[12];
  const float* W2c = (const float*)d_in[13]; const float* b2c = (const float*)d_in[14];
  const float* Wbp1 = (const float*)d_in[15]; const float* bbp1 = (const float*)d_in[16];
  const float* gbp  = (const float*)d_in[17]; const float* bebp = (const float*)d_in[18];
  const float* Wbp2 = (const float*)d_in[19]; const float* bbp2 = (const float*)d_in[20];
  const float* Wcp1 = (const float*)d_in[21]; const float* bcp1 = (const float*)d_in[22];
  const float* gcp  = (const float*)d_in[23]; const float* becp = (const float*)d_in[24];
  const float* Wcp2 = (const float*)d_in[25]; const float* bcp2 = (const float*)d_in[26];
  float* out = (float*)d_out;

  // ---- workspace layout (~74 MB) ----
  ushort* hb   = (ushort*)d_ws;                 // h (bf16, pre-BN); later h2  [N*H]
  ushort* h1b  = hb + (size_t)NN * HH;          // h1; later Uc
  ushort* xwb  = h1b + (size_t)NN * HH;         // xw tmp; later Ub
  ushort* xwc  = xwb + (size_t)NN * HH;         // xw tmp; later Vb
  ushort* vcb  = xwc + (size_t)NN * HH;         // Vc
  ushort* Wt1b = vcb + (size_t)NN * HH;         // 128x128 transposed weights (bf16)
  ushort* Wt1c = Wt1b + 128 * 128;
  ushort* Wt2b = Wt1c + 128 * 128;
  ushort* Wt2c = Wt2b + 128 * 128;
  ushort* Wmb  = Wt2c + 128 * 128;              // MLP W1^T [128][256]
  ushort* Wmc  = Wmb + 256 * 128;
  float* dinv  = (float*)(Wmc + 256 * 128);
  float* dinvb = dinv, *dinvc = dinv + NN;
  float* st    = dinvc + NN;                    // 2048 floats (see layout above)
  int* cnt  = (int*)(st + 2048);
  int* cntb = cnt, *cntc = cnt + NN;
  int* offb = cntc + NN; int* offc = offb + NN;
  int* curb = offc + NN; int* curc = curb + NN;
  int* part = curc + NN;
  int* listb  = part + 2 * SCB;
  int* listc  = listb + EE;
  int* dlistb = listc + EE;
  int* dlistc = dlistb + EE;
  int* elistb = dlistc + EE;
  int* elistc = elistb + EE;

  // ---- degrees + CSR ----
  hipMemsetAsync(cnt, 0, sizeof(int) * 2 * NN, stream);
  hipMemsetAsync(st, 0, sizeof(float) * 2 * HH, stream);
  k_count<<<(2 * EE + 255) / 256, 256, 0, stream>>>(bei, cei, cntb, cntc);
  k_dinv<<<(2 * NN + 255) / 256, 256, 0, stream>>>(cnt, dinv);
  k_scan_part<<<2 * SCB, 256, 0, stream>>>(cnt, part);
  k_scan_base<<<1, 256, 0, stream>>>(part);
  k_scan_off<<<2 * SCB, 256, 0, stream>>>(cnt, part, offb, curb);
  k_fill<<<(2 * EE + 255) / 256, 256, 0, stream>>>(bei, cei, curb, listb, dlistb, elistb,
                                                   curc, listc, dlistc, elistc);

  // ---- encoder + BN (apply fused into layer-1 GEMM) ----
  k_encoder_bf<<<(NN + 63) / 64, 256, 0, stream>>>(x, W_enc, b_enc, hb, st, st + HH);
  k_bn_finalize<<<1, 128, 0, stream>>>(st, st + HH, g_enc, be_enc, st + 512, st + 640, 1.0f / NN);

  // ---- weight transposes (merged) ----
  k_wt_all<<<(4 * 16384 + 2 * 32768 + 255) / 256, 256, 0, stream>>>(
      W1b, W1c, W2b, W2c, Wt1b, Wt1c, Wt2b, Wt2c, Wbp1, Wcp1, Wmb, Wmc);

  int gblk = (NN + 63) / 64;
  int a2blk = (NN + 15) / 16;
  // ---- GCN layer 1 (BN applied on A-read) ----
  k_gemm_bf2<1><<<2 * gblk, 256, 0, stream>>>(hb, Wt1b, xwb, Wt1c, xwc, st + 512, st + 640);
  k_agg2<1><<<a2blk, 256, 0, stream>>>(xwb, xwc, dinvb, dinvc, offb, cntb, listb,
                                       offc, cntc, listc, b1b, b1c, h1b);
  // ---- GCN layer 2 ----
  k_gemm_bf2<0><<<2 * gblk, 256, 0, stream>>>(h1b, Wt2b, xwb, Wt2c, xwc, nullptr, nullptr);
  k_agg2<0><<<a2blk, 256, 0, stream>>>(xwb, xwc, dinvb, dinvc, offb, cntb, listb,
                                       offc, cntc, listc, b2b, b2c, hb);

  // ---- edge predictors: factored concat-GEMM ----
  ushort* Ub = xwb;  ushort* Vb = xwc;   // xw buffers dead after layer-2 agg
  ushort* Uc = h1b;  ushort* Vc = vcb;   // h1 dead after layer-2 gemm
  k_gemm_uv<<<4 * gblk, 256, 0, stream>>>(hb, Wmb, Wmc, Ub, Vb, Uc, Vc);

  hipMemsetAsync(st, 0, sizeof(float) * 4 * HH, stream);
  k_edge_pass1n<<<2 * a2blk, 256, 0, stream>>>(Ub, Vb, Uc, Vc,
                                               offb, cntb, listb, offc, cntc, listc,
                                               bbp1, bcp1, st);
  k_bn_finalize3<<<1, 256, 0, stream>>>(st, gbp, bebp, gcp, becp,
                                        Wbp2, bbp2, Wcp2, bcp2, 1.0f / EE);
  k_edge_pass2n<<<2 * a2blk, 256, 0, stream>>>(Ub, Vb, Uc, Vc,
                                               offb, cntb, listb, elistb,
                                               offc, cntc, listc, elistc,
                                               bbp1, bcp1, st, out);

  k_edge_types<<<(2 * EE + 255) / 256, 256, 0, stream>>>(out);
}

// Round 13
// 366.766 us; speedup vs baseline: 1.2417x; 1.2417x over previous
//
#include <hip/hip_runtime.h>
#include <hip/hip_bf16.h>

#define NN 50000
#define EE 250000
#define HH 128
#define EPS_ 1e-5f
#define SCB 196  // scan segments per relation: ceil(NN/256)

typedef __attribute__((ext_vector_type(8))) short bf16x8;
typedef __attribute__((ext_vector_type(4))) float f32x4;

__device__ __forceinline__ float bf2f(ushort u) {
  union { unsigned int i; float f; } x; x.i = ((unsigned int)u) << 16; return x.f;
}
__device__ __forceinline__ ushort f2bf(float f) {
  union { float f; unsigned int i; } x; x.f = f;
  unsigned int r = (x.i + 0x7fffu + ((x.i >> 16) & 1u)) >> 16;  // RNE, finite inputs
  return (ushort)r;
}

// st float layout:
// 0:sum0 128:sq0 256:sum1 384:sq1 | 512:scale0 640:shift0 768:scale1 896:shift1
// 1024:W2p0[256] 1280:W2p1[256] 1536:b2p0[2] 1538:b2p1[2]

// ---------------- degree / CSR build ----------------
__global__ void k_count(const int* __restrict__ bei, const int* __restrict__ cei,
                        int* __restrict__ cntb, int* __restrict__ cntc) {
  int i = blockIdx.x * blockDim.x + threadIdx.x;
  if (i < EE) atomicAdd(&cntb[bei[EE + i]], 1);
  else if (i < 2 * EE) atomicAdd(&cntc[cei[EE + (i - EE)]], 1);
}

__global__ void k_dinv(const int* __restrict__ cnt, float* __restrict__ dinv) {
  int i = blockIdx.x * blockDim.x + threadIdx.x;  // 2N
  if (i < 2 * NN) dinv[i] = rsqrtf((float)cnt[i] + 1.0f);
}

__global__ void k_scan_part(const int* __restrict__ cnt, int* __restrict__ part) {
  int rel = blockIdx.x / SCB, b = blockIdx.x % SCB;
  int n = b * 256 + threadIdx.x;
  int v = (n < NN) ? cnt[rel * NN + n] : 0;
#pragma unroll
  for (int m = 32; m >= 1; m >>= 1) v += __shfl_xor(v, m, 64);
  __shared__ int red[4];
  if ((threadIdx.x & 63) == 0) red[threadIdx.x >> 6] = v;
  __syncthreads();
  if (threadIdx.x == 0) part[rel * SCB + b] = red[0] + red[1] + red[2] + red[3];
}

__global__ void k_scan_base(int* __restrict__ part) {
  __shared__ int s[256];
  int t = threadIdx.x;
  for (int rel = 0; rel < 2; ++rel) {
    int v = (t < SCB) ? part[rel * SCB + t] : 0;
    s[t] = v;
    __syncthreads();
    for (int ofs = 1; ofs < 256; ofs <<= 1) {
      int x = (t >= ofs) ? s[t - ofs] : 0;
      __syncthreads();
      s[t] += x;
      __syncthreads();
    }
    if (t < SCB) part[rel * SCB + t] = s[t] - v;  // exclusive
    __syncthreads();
  }
}

__global__ void k_scan_off(const int* __restrict__ cnt, const int* __restrict__ part,
                           int* __restrict__ off, int* __restrict__ cur) {
  int rel = blockIdx.x / SCB, b = blockIdx.x % SCB;
  int t = threadIdx.x;
  int n = b * 256 + t;
  int v = (n < NN) ? cnt[rel * NN + n] : 0;
  __shared__ int s[256];
  s[t] = v;
  __syncthreads();
  for (int ofs = 1; ofs < 256; ofs <<= 1) {
    int x = (t >= ofs) ? s[t - ofs] : 0;
    __syncthreads();
    s[t] += x;
    __syncthreads();
  }
  if (n < NN) {
    int o = part[rel * SCB + b] + s[t] - v;
    off[rel * NN + n] = o;
    cur[rel * NN + n] = o;
  }
}

__global__ void k_fill(const int* __restrict__ bei, const int* __restrict__ cei,
                       int* __restrict__ curb, int* __restrict__ listb,
                       int* __restrict__ dlistb, int* __restrict__ elistb,
                       int* __restrict__ curc, int* __restrict__ listc,
                       int* __restrict__ dlistc, int* __restrict__ elistc) {
  int i = blockIdx.x * blockDim.x + threadIdx.x;
  if (i < EE) {
    int dst = bei[EE + i];
    int p = atomicAdd(&curb[dst], 1);
    listb[p] = bei[i];
    dlistb[p] = dst;
    elistb[p] = i;
  } else if (i < 2 * EE) {
    int e = i - EE;
    int dst = cei[EE + e];
    int p = atomicAdd(&curc[dst], 1);
    listc[p] = cei[e];
    dlistc[p] = dst;
    elistc[p] = e;
  }
}

// ---------------- encoder: relu(x@W_enc+b) -> bf16 (pre-BN), accumulate BN stats ----------------
__global__ void k_encoder_bf(const float* __restrict__ x, const float* __restrict__ W,
                             const float* __restrict__ b, ushort* __restrict__ hb,
                             float* __restrict__ sum, float* __restrict__ sumsq) {
  int t = threadIdx.x;
  int c = t & 127, r = t >> 7;
  int n0 = blockIdx.x * 64;
  float w0 = W[c], w1 = W[HH + c], w2 = W[2 * HH + c], bb = b[c];
  float ls = 0.f, lss = 0.f;
  for (int rr = r; rr < 64; rr += 2) {
    int n = n0 + rr;
    if (n < NN) {
      float v = fmaxf(x[n * 3] * w0 + x[n * 3 + 1] * w1 + x[n * 3 + 2] * w2 + bb, 0.f);
      ushort u = f2bf(v);
      hb[(size_t)n * HH + c] = u;
      float vr = bf2f(u);
      ls += vr; lss += vr * vr;
    }
  }
  __shared__ float red[2][HH];
  red[r][c] = ls; __syncthreads();
  if (r == 0) atomicAdd(&sum[c], red[0][c] + red[1][c]);
  __syncthreads();
  red[r][c] = lss; __syncthreads();
  if (r == 0) atomicAdd(&sumsq[c], red[0][c] + red[1][c]);
}

__global__ void k_bn_finalize(const float* __restrict__ sum, const float* __restrict__ sumsq,
                              const float* __restrict__ g, const float* __restrict__ be,
                              float* __restrict__ scale, float* __restrict__ shift, float invn) {
  int c = threadIdx.x;
  float m = sum[c] * invn;
  float v = fmaxf(sumsq[c] * invn - m * m, 0.f);
  float s = g[c] * rsqrtf(v + EPS_);
  scale[c] = s;
  shift[c] = be[c] - m * s;
}

// 2-relation finalize + BN-folded W2 (W2p = scale*W2, b2p = b2 + shift@W2)
__global__ void k_bn_finalize3(float* __restrict__ st, const float* __restrict__ g0,
                               const float* __restrict__ be0, const float* __restrict__ g1,
                               const float* __restrict__ be1,
                               const float* __restrict__ W2_0, const float* __restrict__ b2_0,
                               const float* __restrict__ W2_1, const float* __restrict__ b2_1,
                               float invn) {
  int t = threadIdx.x;  // 256
  int rel = t >> 7, c = t & 127;
  const float* sum = st + rel * 2 * HH;
  const float* sq  = sum + HH;
  float* scale = st + 512 + rel * 256;
  float* shift = scale + HH;
  const float* g = rel ? g1 : g0;
  const float* be = rel ? be1 : be0;
  const float* W2 = rel ? W2_1 : W2_0;
  float m = sum[c] * invn;
  float v = fmaxf(sq[c] * invn - m * m, 0.f);
  float sc = g[c] * rsqrtf(v + EPS_);
  float sh = be[c] - m * sc;
  scale[c] = sc;
  shift[c] = sh;
  float w20 = W2[c * 2], w21 = W2[c * 2 + 1];
  st[1024 + rel * 256 + c * 2 + 0] = sc * w20;
  st[1024 + rel * 256 + c * 2 + 1] = sc * w21;
  __shared__ float red[2][HH][2];
  red[rel][c][0] = sh * w20;
  red[rel][c][1] = sh * w21;
  __syncthreads();
  if (c < 2) {
    float s = 0.f;
    for (int i = 0; i < HH; ++i) s += red[rel][i][c];
    st[1536 + rel * 2 + c] = (rel ? b2_1 : b2_0)[c] + s;
  }
}

// ---------------- weight transposes to bf16 (merged) ----------------
__global__ void k_wt_all(const float* __restrict__ s0, const float* __restrict__ s1,
                         const float* __restrict__ s2, const float* __restrict__ s3,
                         ushort* __restrict__ d0, ushort* __restrict__ d1,
                         ushort* __restrict__ d2, ushort* __restrict__ d3,
                         const float* __restrict__ m0, const float* __restrict__ m1,
                         ushort* __restrict__ e0, ushort* __restrict__ e1) {
  int i = blockIdx.x * 256 + threadIdx.x;
  if (i < 4 * 16384) {
    int sel = i >> 14, loc = i & 16383;
    int k = loc >> 7, c = loc & 127;
    const float* s = sel == 0 ? s0 : sel == 1 ? s1 : sel == 2 ? s2 : s3;
    ushort* d = sel == 0 ? d0 : sel == 1 ? d1 : sel == 2 ? d2 : d3;
    d[c * 128 + k] = f2bf(s[loc]);
  } else if (i < 4 * 16384 + 2 * 32768) {
    int j = i - 4 * 16384;
    int sel = j >> 15, loc = j & 32767;
    int k = loc >> 7, c = loc & 127;
    const float* s = sel ? m1 : m0;
    ushort* d = sel ? e1 : e0;
    d[c * 256 + k] = f2bf(s[loc]);
  }
}

// ---------------- bf16 GEMM pair (optional fused BN on A-read) ----------------
template <int APPLYBN>
__global__ __launch_bounds__(256) void k_gemm_bf2(const ushort* __restrict__ X,
                                                  const ushort* __restrict__ Wt0,
                                                  ushort* __restrict__ Y0,
                                                  const ushort* __restrict__ Wt1,
                                                  ushort* __restrict__ Y1,
                                                  const float* __restrict__ bnsc,
                                                  const float* __restrict__ bnsh) {
  const int nb = gridDim.x >> 1;
  const int rel = blockIdx.x >= nb;
  const int blk = rel ? blockIdx.x - nb : blockIdx.x;
  const ushort* Wt = rel ? Wt1 : Wt0;
  ushort* Y = rel ? Y1 : Y0;
  const int t = threadIdx.x;
  const int l = t & 63, wid = t >> 6;
  const int wm = wid >> 1, wn = wid & 1;
  const int lr = l & 15, lg = l >> 4;
  const int n0 = blk * 64;
  f32x4 acc[2][4];
#pragma unroll
  for (int mf = 0; mf < 2; ++mf)
#pragma unroll
    for (int nf = 0; nf < 4; ++nf) acc[mf][nf] = (f32x4){0.f, 0.f, 0.f, 0.f};
  int r0 = n0 + wm * 32 + lr;
  int rA = min(r0, NN - 1), rB = min(r0 + 16, NN - 1);
  const ushort* xa = X + (size_t)rA * HH + lg * 8;
  const ushort* xb = X + (size_t)rB * HH + lg * 8;
#pragma unroll
  for (int ks = 0; ks < 4; ++ks) {
    bf16x8 a0 = *(const bf16x8*)(xa + ks * 32);
    bf16x8 a1 = *(const bf16x8*)(xb + ks * 32);
    if (APPLYBN) {
      int k0 = ks * 32 + lg * 8;
#pragma unroll
      for (int i = 0; i < 8; ++i) {
        float sc = bnsc[k0 + i], sh = bnsh[k0 + i];
        a0[i] = (short)f2bf(bf2f((ushort)a0[i]) * sc + sh);
        a1[i] = (short)f2bf(bf2f((ushort)a1[i]) * sc + sh);
      }
    }
#pragma unroll
    for (int nf = 0; nf < 4; ++nf) {
      int col = wn * 64 + nf * 16 + lr;
      bf16x8 b = *(const bf16x8*)(Wt + col * 128 + ks * 32 + lg * 8);
      acc[0][nf] = __builtin_amdgcn_mfma_f32_16x16x32_bf16(a0, b, acc[0][nf], 0, 0, 0);
      acc[1][nf] = __builtin_amdgcn_mfma_f32_16x16x32_bf16(a1, b, acc[1][nf], 0, 0, 0);
    }
  }
#pragma unroll
  for (int mf = 0; mf < 2; ++mf)
#pragma unroll
    for (int nf = 0; nf < 4; ++nf) {
      int col = wn * 64 + nf * 16 + lr;
#pragma unroll
      for (int j = 0; j < 4; ++j) {
        int row = n0 + wm * 32 + mf * 16 + lg * 4 + j;
        if (row < NN) Y[(size_t)row * HH + col] = f2bf(acc[mf][nf][j]);
      }
    }
}

// ---------------- UV GEMMs: U=h2@W1_top, V=h2@W1_bot per relation ----------------
__global__ __launch_bounds__(256) void k_gemm_uv(const ushort* __restrict__ X,
                                                 const ushort* __restrict__ Wm0,
                                                 const ushort* __restrict__ Wm1,
                                                 ushort* __restrict__ U0, ushort* __restrict__ V0,
                                                 ushort* __restrict__ U1, ushort* __restrict__ V1) {
  const int nb = gridDim.x >> 2;
  const int sel = blockIdx.x / nb;
  const int blk = blockIdx.x - sel * nb;
  const ushort* Wm = (sel >> 1) ? Wm1 : Wm0;
  const int koff = (sel & 1) * 128;
  ushort* Y = sel == 0 ? U0 : sel == 1 ? V0 : sel == 2 ? U1 : V1;
  const int t = threadIdx.x;
  const int l = t & 63, wid = t >> 6;
  const int wm = wid >> 1, wn = wid & 1;
  const int lr = l & 15, lg = l >> 4;
  const int n0 = blk * 64;
  f32x4 acc[2][4];
#pragma unroll
  for (int mf = 0; mf < 2; ++mf)
#pragma unroll
    for (int nf = 0; nf < 4; ++nf) acc[mf][nf] = (f32x4){0.f, 0.f, 0.f, 0.f};
  int r0 = n0 + wm * 32 + lr;
  int rA = min(r0, NN - 1), rB = min(r0 + 16, NN - 1);
  const ushort* xa = X + (size_t)rA * HH + lg * 8;
  const ushort* xb = X + (size_t)rB * HH + lg * 8;
#pragma unroll
  for (int ks = 0; ks < 4; ++ks) {
    bf16x8 a0 = *(const bf16x8*)(xa + ks * 32);
    bf16x8 a1 = *(const bf16x8*)(xb + ks * 32);
#pragma unroll
    for (int nf = 0; nf < 4; ++nf) {
      int col = wn * 64 + nf * 16 + lr;
      bf16x8 b = *(const bf16x8*)(Wm + col * 256 + koff + ks * 32 + lg * 8);
      acc[0][nf] = __builtin_amdgcn_mfma_f32_16x16x32_bf16(a0, b, acc[0][nf], 0, 0, 0);
      acc[1][nf] = __builtin_amdgcn_mfma_f32_16x16x32_bf16(a1, b, acc[1][nf], 0, 0, 0);
    }
  }
#pragma unroll
  for (int mf = 0; mf < 2; ++mf)
#pragma unroll
    for (int nf = 0; nf < 4; ++nf) {
      int col = wn * 64 + nf * 16 + lr;
#pragma unroll
      for (int j = 0; j < 4; ++j) {
        int row = n0 + wm * 32 + mf * 16 + lg * 4 + j;
        if (row < NN) Y[(size_t)row * HH + col] = f2bf(acc[mf][nf][j]);
      }
    }
}

// ---------------- fused aggregation v2: 16 nodes/block, 16 lanes x 8 cols, unroll-4 ----------------
template <int RELU>
__global__ __launch_bounds__(256) void k_agg2(
    const ushort* __restrict__ xwb, const ushort* __restrict__ xwc,
    const float* __restrict__ dinvb, const float* __restrict__ dinvc,
    const int* __restrict__ offb, const int* __restrict__ cntb,
    const int* __restrict__ listb,
    const int* __restrict__ offc, const int* __restrict__ cntc,
    const int* __restrict__ listc,
    const float* __restrict__ bb, const float* __restrict__ bc,
    ushort* __restrict__ out) {
  const int t = threadIdx.x;
  const int ln = t & 15;            // lane-within-node: cols ln*8 .. +7
  const int n = blockIdx.x * 16 + (t >> 4);
  if (n >= NN) return;
  const int c0 = ln * 8;
  float dnb = dinvb[n], dnc = dinvc[n];
  bf16x8 sb = *(const bf16x8*)(xwb + (size_t)n * HH + c0);
  bf16x8 sc = *(const bf16x8*)(xwc + (size_t)n * HH + c0);
  float acc[8];
#pragma unroll
  for (int i = 0; i < 8; ++i)
    acc[i] = bb[c0 + i] + bc[c0 + i] + dnb * dnb * bf2f((ushort)sb[i])
                                     + dnc * dnc * bf2f((ushort)sc[i]);
  // ---- relation b ----
  {
    int o = offb[n], e = o + cntb[n];
    float s[8];
#pragma unroll
    for (int i = 0; i < 8; ++i) s[i] = 0.f;
    for (; o + 4 <= e; o += 4) {
      int i0 = listb[o], i1 = listb[o + 1], i2 = listb[o + 2], i3 = listb[o + 3];
      float w0 = dinvb[i0], w1 = dinvb[i1], w2 = dinvb[i2], w3 = dinvb[i3];
      bf16x8 r0 = *(const bf16x8*)(xwb + (size_t)i0 * HH + c0);
      bf16x8 r1 = *(const bf16x8*)(xwb + (size_t)i1 * HH + c0);
      bf16x8 r2 = *(const bf16x8*)(xwb + (size_t)i2 * HH + c0);
      bf16x8 r3 = *(const bf16x8*)(xwb + (size_t)i3 * HH + c0);
#pragma unroll
      for (int i = 0; i < 8; ++i)
        s[i] += w0 * bf2f((ushort)r0[i]) + w1 * bf2f((ushort)r1[i])
              + w2 * bf2f((ushort)r2[i]) + w3 * bf2f((ushort)r3[i]);
    }
    for (; o < e; ++o) {
      int src = listb[o];
      float w = dinvb[src];
      bf16x8 r = *(const bf16x8*)(xwb + (size_t)src * HH + c0);
#pragma unroll
      for (int i = 0; i < 8; ++i) s[i] += w * bf2f((ushort)r[i]);
    }
#pragma unroll
    for (int i = 0; i < 8; ++i) acc[i] += dnb * s[i];
  }
  // ---- relation c ----
  {
    int o = offc[n], e = o + cntc[n];
    float s[8];
#pragma unroll
    for (int i = 0; i < 8; ++i) s[i] = 0.f;
    for (; o + 4 <= e; o += 4) {
      int i0 = listc[o], i1 = listc[o + 1], i2 = listc[o + 2], i3 = listc[o + 3];
      float w0 = dinvc[i0], w1 = dinvc[i1], w2 = dinvc[i2], w3 = dinvc[i3];
      bf16x8 r0 = *(const bf16x8*)(xwc + (size_t)i0 * HH + c0);
      bf16x8 r1 = *(const bf16x8*)(xwc + (size_t)i1 * HH + c0);
      bf16x8 r2 = *(const bf16x8*)(xwc + (size_t)i2 * HH + c0);
      bf16x8 r3 = *(const bf16x8*)(xwc + (size_t)i3 * HH + c0);
#pragma unroll
      for (int i = 0; i < 8; ++i)
        s[i] += w0 * bf2f((ushort)r0[i]) + w1 * bf2f((ushort)r1[i])
              + w2 * bf2f((ushort)r2[i]) + w3 * bf2f((ushort)r3[i]);
    }
    for (; o < e; ++o) {
      int src = listc[o];
      float w = dinvc[src];
      bf16x8 r = *(const bf16x8*)(xwc + (size_t)src * HH + c0);
#pragma unroll
      for (int i = 0; i < 8; ++i) s[i] += w * bf2f((ushort)r[i]);
    }
#pragma unroll
    for (int i = 0; i < 8; ++i) acc[i] += dnc * s[i];
  }
  bf16x8 ov;
#pragma unroll
  for (int i = 0; i < 8; ++i) {
    float v = RELU ? fmaxf(acc[i], 0.f) : acc[i];
    ov[i] = (short)f2bf(v);
  }
  *(bf16x8*)(out + (size_t)n * HH + c0) = ov;
}

// ---------------- edge pass 1 (edge-centric, 2-edge ILP): stats of relu(U[s]+V[d]+b1) ----------------
// 256 threads = 32 edge slots x 8 col-groups of 16; each thread handles edges p and p+32
// per grid-stride iteration (8 independent 16B gathers in flight).
__global__ __launch_bounds__(256) void k_edge_pass1e(
    const ushort* __restrict__ U0, const ushort* __restrict__ V0,
    const ushort* __restrict__ U1, const ushort* __restrict__ V1,
    const int* __restrict__ sl0, const int* __restrict__ dl0,
    const int* __restrict__ sl1, const int* __restrict__ dl1,
    const float* __restrict__ b1_0, const float* __restrict__ b1_1,
    float* __restrict__ st) {
  const int nbk = gridDim.x >> 1;
  const int rel = blockIdx.x >= nbk;
  const int blk = rel ? blockIdx.x - nbk : blockIdx.x;
  const ushort* U = rel ? U1 : U0;
  const ushort* V = rel ? V1 : V0;
  const int* sl = rel ? sl1 : sl0;
  const int* dl = rel ? dl1 : dl0;
  const float* b1 = rel ? b1_1 : b1_0;

  __shared__ float b1s[HH], redA[HH], redB[HH];
  const int t = threadIdx.x;
  if (t < HH) { b1s[t] = b1[t]; redA[t] = 0.f; redB[t] = 0.f; }
  __syncthreads();
  const int cg = t & 7, el = t >> 3;
  const int c0 = cg * 16;

  float ls[16], lss[16];
#pragma unroll
  for (int i = 0; i < 16; ++i) { ls[i] = 0.f; lss[i] = 0.f; }

  for (int p0 = blk * 64; p0 < EE; p0 += nbk * 64) {
    int pA = p0 + el, pB = p0 + 32 + el;
    if (pB < EE) {  // common path: both edges valid
      int sA = sl[pA], dA = dl[pA], sB = sl[pB], dB = dl[pB];
      bf16x8 uA0 = *(const bf16x8*)(U + (size_t)sA * HH + c0);
      bf16x8 uA1 = *(const bf16x8*)(U + (size_t)sA * HH + c0 + 8);
      bf16x8 vA0 = *(const bf16x8*)(V + (size_t)dA * HH + c0);
      bf16x8 vA1 = *(const bf16x8*)(V + (size_t)dA * HH + c0 + 8);
      bf16x8 uB0 = *(const bf16x8*)(U + (size_t)sB * HH + c0);
      bf16x8 uB1 = *(const bf16x8*)(U + (size_t)sB * HH + c0 + 8);
      bf16x8 vB0 = *(const bf16x8*)(V + (size_t)dB * HH + c0);
      bf16x8 vB1 = *(const bf16x8*)(V + (size_t)dB * HH + c0 + 8);
#pragma unroll
      for (int i = 0; i < 8; ++i) {
        float rA = fmaxf(bf2f((ushort)uA0[i]) + bf2f((ushort)vA0[i]) + b1s[c0 + i], 0.f);
        float rB = fmaxf(bf2f((ushort)uB0[i]) + bf2f((ushort)vB0[i]) + b1s[c0 + i], 0.f);
        ls[i] += rA + rB; lss[i] += rA * rA + rB * rB;
        float rA2 = fmaxf(bf2f((ushort)uA1[i]) + bf2f((ushort)vA1[i]) + b1s[c0 + 8 + i], 0.f);
        float rB2 = fmaxf(bf2f((ushort)uB1[i]) + bf2f((ushort)vB1[i]) + b1s[c0 + 8 + i], 0.f);
        ls[8 + i] += rA2 + rB2; lss[8 + i] += rA2 * rA2 + rB2 * rB2;
      }
    } else if (pA < EE) {  // tail: only edge A valid
      int sA = sl[pA], dA = dl[pA];
      bf16x8 uA0 = *(const bf16x8*)(U + (size_t)sA * HH + c0);
      bf16x8 uA1 = *(const bf16x8*)(U + (size_t)sA * HH + c0 + 8);
      bf16x8 vA0 = *(const bf16x8*)(V + (size_t)dA * HH + c0);
      bf16x8 vA1 = *(const bf16x8*)(V + (size_t)dA * HH + c0 + 8);
#pragma unroll
      for (int i = 0; i < 8; ++i) {
        float rA = fmaxf(bf2f((ushort)uA0[i]) + bf2f((ushort)vA0[i]) + b1s[c0 + i], 0.f);
        ls[i] += rA; lss[i] += rA * rA;
        float rA2 = fmaxf(bf2f((ushort)uA1[i]) + bf2f((ushort)vA1[i]) + b1s[c0 + 8 + i], 0.f);
        ls[8 + i] += rA2; lss[8 + i] += rA2 * rA2;
      }
    }
  }
  // reduce over the wave's 8 edge slots (lane bits 3,4,5)
#pragma unroll
  for (int m = 8; m <= 32; m <<= 1)
#pragma unroll
    for (int i = 0; i < 16; ++i) {
      ls[i] += __shfl_xor(ls[i], m, 64);
      lss[i] += __shfl_xor(lss[i], m, 64);
    }
  if ((t & 63) < 8) {
#pragma unroll
    for (int i = 0; i < 16; ++i) {
      atomicAdd(&redA[c0 + i], ls[i]);
      atomicAdd(&redB[c0 + i], lss[i]);
    }
  }
  __syncthreads();
  if (t < HH) {
    atomicAdd(&st[rel * 2 * HH + t], redA[t]);
    atomicAdd(&st[rel * 2 * HH + HH + t], redB[t]);
  }
}

// ---------------- edge pass 2 (edge-centric, 2-edge ILP): out = relu(U[s]+V[d]+b1) @ W2p + b2p ----------------
__global__ __launch_bounds__(256) void k_edge_pass2e(
    const ushort* __restrict__ U0, const ushort* __restrict__ V0,
    const ushort* __restrict__ U1, const ushort* __restrict__ V1,
    const int* __restrict__ sl0, const int* __restrict__ dl0, const int* __restrict__ el0,
    const int* __restrict__ sl1, const int* __restrict__ dl1, const int* __restrict__ el1,
    const float* __restrict__ b1_0, const float* __restrict__ b1_1,
    const float* __restrict__ st, float* __restrict__ out) {
  const int nbk = gridDim.x >> 1;
  const int rel = blockIdx.x >= nbk;
  const int blk = rel ? blockIdx.x - nbk : blockIdx.x;
  const ushort* U = rel ? U1 : U0;
  const ushort* V = rel ? V1 : V0;
  const int* sl = rel ? sl1 : sl0;
  const int* dl = rel ? dl1 : dl0;
  const int* el = rel ? el1 : el0;
  const float* b1 = rel ? b1_1 : b1_0;
  float* o_ = out + (size_t)rel * 2 * EE;

  __shared__ float b1s[HH], w2s[256], b2s[2];
  const int t = threadIdx.x;
  if (t < HH) b1s[t] = b1[t];
  w2s[t] = st[1024 + rel * 256 + t];
  if (t < 2) b2s[t] = st[1536 + rel * 2 + t];
  __syncthreads();
  const int cg = t & 7, es = t >> 3;
  const int c0 = cg * 16;

  int pA = blk * 64 + es;
  int pB = pA + 32;
  bool okA = pA < EE, okB = pB < EE;
  int sA = okA ? sl[pA] : 0, dA = okA ? dl[pA] : 0;
  int sB = okB ? sl[pB] : 0, dB = okB ? dl[pB] : 0;

  bf16x8 uA0 = *(const bf16x8*)(U + (size_t)sA * HH + c0);
  bf16x8 uA1 = *(const bf16x8*)(U + (size_t)sA * HH + c0 + 8);
  bf16x8 vA0 = *(const bf16x8*)(V + (size_t)dA * HH + c0);
  bf16x8 vA1 = *(const bf16x8*)(V + (size_t)dA * HH + c0 + 8);
  bf16x8 uB0 = *(const bf16x8*)(U + (size_t)sB * HH + c0);
  bf16x8 uB1 = *(const bf16x8*)(U + (size_t)sB * HH + c0 + 8);
  bf16x8 vB0 = *(const bf16x8*)(V + (size_t)dB * HH + c0);
  bf16x8 vB1 = *(const bf16x8*)(V + (size_t)dB * HH + c0 + 8);

  float pa0 = 0.f, pa1 = 0.f, pb0 = 0.f, pb1 = 0.f;
#pragma unroll
  for (int i = 0; i < 8; ++i) {
    float wa = w2s[(c0 + i) * 2], wb = w2s[(c0 + i) * 2 + 1];
    float rA = fmaxf(bf2f((ushort)uA0[i]) + bf2f((ushort)vA0[i]) + b1s[c0 + i], 0.f);
    pa0 += rA * wa; pa1 += rA * wb;
    float rB = fmaxf(bf2f((ushort)uB0[i]) + bf2f((ushort)vB0[i]) + b1s[c0 + i], 0.f);
    pb0 += rB * wa; pb1 += rB * wb;
    float wa2 = w2s[(c0 + 8 + i) * 2], wb2 = w2s[(c0 + 8 + i) * 2 + 1];
    float rA2 = fmaxf(bf2f((ushort)uA1[i]) + bf2f((ushort)vA1[i]) + b1s[c0 + 8 + i], 0.f);
    pa0 += rA2 * wa2; pa1 += rA2 * wb2;
    float rB2 = fmaxf(bf2f((ushort)uB1[i]) + bf2f((ushort)vB1[i]) + b1s[c0 + 8 + i], 0.f);
    pb0 += rB2 * wa2; pb1 += rB2 * wb2;
  }
  // reduce across the 8 col-groups of each edge (lane bits 0..2)
#pragma unroll
  for (int m = 4; m >= 1; m >>= 1) {
    pa0 += __shfl_xor(pa0, m, 64); pa1 += __shfl_xor(pa1, m, 64);
    pb0 += __shfl_xor(pb0, m, 64); pb1 += __shfl_xor(pb1, m, 64);
  }
  if (cg == 0) {
    float b20 = b2s[0], b21 = b2s[1];
    if (okA) {
      int eid = el[pA];
      o_[(size_t)eid * 2 + 0] = pa0 + b20;
      o_[(size_t)eid * 2 + 1] = pa1 + b21;
    }
    if (okB) {
      int eid = el[pB];
      o_[(size_t)eid * 2 + 0] = pb0 + b20;
      o_[(size_t)eid * 2 + 1] = pb1 + b21;
    }
  }
}

// ---------------- edge types ----------------
__global__ void k_edge_types(float* __restrict__ out) {
  int i = blockIdx.x * 256 + threadIdx.x;
  if (i < 2 * EE) out[(size_t)2 * EE * 2 + i] = (i < EE) ? 0.0f : 1.0f;
}

extern "C" void kernel_launch(void* const* d_in, const int* in_sizes, int n_in,
                              void* d_out, int out_size, void* d_ws, size_t ws_size,
                              hipStream_t stream) {
  const float* x      = (const float*)d_in[0];
  const int*   bei    = (const int*)d_in[1];
  const int*   cei    = (const int*)d_in[2];
  const float* W_enc  = (const float*)d_in[3];
  const float* b_enc  = (const float*)d_in[4];
  const float* g_enc  = (const float*)d_in[5];
  const float* be_enc = (const float*)d_in[6];
  const float* W1b = (const float*)d_in[7];  const float* b1b = (const float*)d_in[8];
  const float* W1c = (const float*)d_in[9];  const float* b1c = (const float*)d_in[10];
  const float* W2b = (const float*)d_in[11]; const float* b2b = (const float*)d_in[12];
  const float* W2c = (const float*)d_in[13]; const float* b2c = (const float*)d_in[14];
  const float* Wbp1 = (const float*)d_in[15]; const float* bbp1 = (const float*)d_in[16];
  const float* gbp  = (const float*)d_in[17]; const float* bebp = (const float*)d_in[18];
  const float* Wbp2 = (const float*)d_in[19]; const float* bbp2 = (const float*)d_in[20];
  const float* Wcp1 = (const float*)d_in[21]; const float* bcp1 = (const float*)d_in[22];
  const float* gcp  = (const float*)d_in[23]; const float* becp = (const float*)d_in[24];
  const float* Wcp2 = (const float*)d_in[25]; const float* bcp2 = (const float*)d_in[26];
  float* out = (float*)d_out;

  // ---- workspace layout (~74 MB) ----
  ushort* hb   = (ushort*)d_ws;                 // h (bf16, pre-BN); later h2  [N*H]
  ushort* h1b  = hb + (size_t)NN * HH;          // h1; later Uc
  ushort* xwb  = h1b + (size_t)NN * HH;         // xw tmp; later Ub
  ushort* xwc  = xwb + (size_t)NN * HH;         // xw tmp; later Vb
  ushort* vcb  = xwc + (size_t)NN * HH;         // Vc
  ushort* Wt1b = vcb + (size_t)NN * HH;         // 128x128 transposed weights (bf16)
  ushort* Wt1c = Wt1b + 128 * 128;
  ushort* Wt2b = Wt1c + 128 * 128;
  ushort* Wt2c = Wt2b + 128 * 128;
  ushort* Wmb  = Wt2c + 128 * 128;              // MLP W1^T [128][256]
  ushort* Wmc  = Wmb + 256 * 128;
  float* dinv  = (float*)(Wmc + 256 * 128);
  float* dinvb = dinv, *dinvc = dinv + NN;
  float* st    = dinvc + NN;                    // 2048 floats (see layout above)
  int* cnt  = (int*)(st + 2048);
  int* cntb = cnt, *cntc = cnt + NN;
  int* offb = cntc + NN; int* offc = offb + NN;
  int* curb = offc + NN; int* curc = curb + NN;
  int* part = curc + NN;
  int* listb  = part + 2 * SCB;
  int* listc  = listb + EE;
  int* dlistb = listc + EE;
  int* dlistc = dlistb + EE;
  int* elistb = dlistc + EE;
  int* elistc = elistb + EE;

  // ---- degrees + CSR ----
  hipMemsetAsync(cnt, 0, sizeof(int) * 2 * NN, stream);
  hipMemsetAsync(st, 0, sizeof(float) * 2 * HH, stream);
  k_count<<<(2 * EE + 255) / 256, 256, 0, stream>>>(bei, cei, cntb, cntc);
  k_dinv<<<(2 * NN + 255) / 256, 256, 0, stream>>>(cnt, dinv);
  k_scan_part<<<2 * SCB, 256, 0, stream>>>(cnt, part);
  k_scan_base<<<1, 256, 0, stream>>>(part);
  k_scan_off<<<2 * SCB, 256, 0, stream>>>(cnt, part, offb, curb);
  k_fill<<<(2 * EE + 255) / 256, 256, 0, stream>>>(bei, cei, curb, listb, dlistb, elistb,
                                                   curc, listc, dlistc, elistc);

  // ---- encoder + BN (apply fused into layer-1 GEMM) ----
  k_encoder_bf<<<(NN + 63) / 64, 256, 0, stream>>>(x, W_enc, b_enc, hb, st, st + HH);
  k_bn_finalize<<<1, 128, 0, stream>>>(st, st + HH, g_enc, be_enc, st + 512, st + 640, 1.0f / NN);

  // ---- weight transposes (merged) ----
  k_wt_all<<<(4 * 16384 + 2 * 32768 + 255) / 256, 256, 0, stream>>>(
      W1b, W1c, W2b, W2c, Wt1b, Wt1c, Wt2b, Wt2c, Wbp1, Wcp1, Wmb, Wmc);

  int gblk = (NN + 63) / 64;
  int a2blk = (NN + 15) / 16;
  // ---- GCN layer 1 (BN applied on A-read) ----
  k_gemm_bf2<1><<<2 * gblk, 256, 0, stream>>>(hb, Wt1b, xwb, Wt1c, xwc, st + 512, st + 640);
  k_agg2<1><<<a2blk, 256, 0, stream>>>(xwb, xwc, dinvb, dinvc, offb, cntb, listb,
                                       offc, cntc, listc, b1b, b1c, h1b);
  // ---- GCN layer 2 ----
  k_gemm_bf2<0><<<2 * gblk, 256, 0, stream>>>(h1b, Wt2b, xwb, Wt2c, xwc, nullptr, nullptr);
  k_agg2<0><<<a2blk, 256, 0, stream>>>(xwb, xwc, dinvb, dinvc, offb, cntb, listb,
                                       offc, cntc, listc, b2b, b2c, hb);

  // ---- edge predictors: factored concat-GEMM ----
  ushort* Ub = xwb;  ushort* Vb = xwc;   // xw buffers dead after layer-2 agg
  ushort* Uc = h1b;  ushort* Vc = vcb;   // h1 dead after layer-2 gemm
  k_gemm_uv<<<4 * gblk, 256, 0, stream>>>(hb, Wmb, Wmc, Ub, Vb, Uc, Vc);

  hipMemsetAsync(st, 0, sizeof(float) * 4 * HH, stream);
  int p1b = 1024;                                   // grid-stride blocks per relation
  k_edge_pass1e<<<2 * p1b, 256, 0, stream>>>(Ub, Vb, Uc, Vc, listb, dlistb, listc, dlistc,
                                             bbp1, bcp1, st);
  k_bn_finalize3<<<1, 256, 0, stream>>>(st, gbp, bebp, gcp, becp,
                                        Wbp2, bbp2, Wcp2, bcp2, 1.0f / EE);
  int p2b = (EE + 63) / 64;
  k_edge_pass2e<<<2 * p2b, 256, 0, stream>>>(Ub, Vb, Uc, Vc,
                                             listb, dlistb, elistb, listc, dlistc, elistc,
                                             bbp1, bcp1, st, out);

  k_edge_types<<<(2 * EE + 255) / 256, 256, 0, stream>>>(out);
}

// Round 14
// 364.127 us; speedup vs baseline: 1.2507x; 1.0072x over previous
//
#include <hip/hip_runtime.h>
#include <hip/hip_bf16.h>

#define NN 50000
#define EE 250000
#define HH 128
#define EPS_ 1e-5f
#define SCB 196  // scan segments per relation: ceil(NN/256)

typedef __attribute__((ext_vector_type(8))) short bf16x8;
typedef __attribute__((ext_vector_type(4))) float f32x4;

__device__ __forceinline__ float bf2f(ushort u) {
  union { unsigned int i; float f; } x; x.i = ((unsigned int)u) << 16; return x.f;
}
__device__ __forceinline__ ushort f2bf(float f) {
  union { float f; unsigned int i; } x; x.f = f;
  unsigned int r = (x.i + 0x7fffu + ((x.i >> 16) & 1u)) >> 16;  // RNE, finite inputs
  return (ushort)r;
}

// st float layout:
// 0:sum0 128:sq0 256:sum1 384:sq1 | 512:scale0 640:shift0 768:scale1 896:shift1
// 1024:W2p0[256] 1280:W2p1[256] 1536:b2p0[2] 1538:b2p1[2]

// ---------------- degree / CSR build ----------------
__global__ void k_count(const int* __restrict__ bei, const int* __restrict__ cei,
                        int* __restrict__ cntb, int* __restrict__ cntc) {
  int i = blockIdx.x * blockDim.x + threadIdx.x;
  if (i < EE) atomicAdd(&cntb[bei[EE + i]], 1);
  else if (i < 2 * EE) atomicAdd(&cntc[cei[EE + (i - EE)]], 1);
}

__global__ void k_dinv(const int* __restrict__ cnt, float* __restrict__ dinv) {
  int i = blockIdx.x * blockDim.x + threadIdx.x;  // 2N
  if (i < 2 * NN) dinv[i] = rsqrtf((float)cnt[i] + 1.0f);
}

__global__ void k_scan_part(const int* __restrict__ cnt, int* __restrict__ part) {
  int rel = blockIdx.x / SCB, b = blockIdx.x % SCB;
  int n = b * 256 + threadIdx.x;
  int v = (n < NN) ? cnt[rel * NN + n] : 0;
#pragma unroll
  for (int m = 32; m >= 1; m >>= 1) v += __shfl_xor(v, m, 64);
  __shared__ int red[4];
  if ((threadIdx.x & 63) == 0) red[threadIdx.x >> 6] = v;
  __syncthreads();
  if (threadIdx.x == 0) part[rel * SCB + b] = red[0] + red[1] + red[2] + red[3];
}

__global__ void k_scan_base(int* __restrict__ part) {
  __shared__ int s[256];
  int t = threadIdx.x;
  for (int rel = 0; rel < 2; ++rel) {
    int v = (t < SCB) ? part[rel * SCB + t] : 0;
    s[t] = v;
    __syncthreads();
    for (int ofs = 1; ofs < 256; ofs <<= 1) {
      int x = (t >= ofs) ? s[t - ofs] : 0;
      __syncthreads();
      s[t] += x;
      __syncthreads();
    }
    if (t < SCB) part[rel * SCB + t] = s[t] - v;  // exclusive
    __syncthreads();
  }
}

__global__ void k_scan_off(const int* __restrict__ cnt, const int* __restrict__ part,
                           int* __restrict__ off, int* __restrict__ cur) {
  int rel = blockIdx.x / SCB, b = blockIdx.x % SCB;
  int t = threadIdx.x;
  int n = b * 256 + t;
  int v = (n < NN) ? cnt[rel * NN + n] : 0;
  __shared__ int s[256];
  s[t] = v;
  __syncthreads();
  for (int ofs = 1; ofs < 256; ofs <<= 1) {
    int x = (t >= ofs) ? s[t - ofs] : 0;
    __syncthreads();
    s[t] += x;
    __syncthreads();
  }
  if (n < NN) {
    int o = part[rel * SCB + b] + s[t] - v;
    off[rel * NN + n] = o;
    cur[rel * NN + n] = o;
  }
}

__global__ void k_fill(const int* __restrict__ bei, const int* __restrict__ cei,
                       int* __restrict__ curb, int* __restrict__ listb,
                       int* __restrict__ dlistb, int* __restrict__ elistb,
                       int* __restrict__ curc, int* __restrict__ listc,
                       int* __restrict__ dlistc, int* __restrict__ elistc) {
  int i = blockIdx.x * blockDim.x + threadIdx.x;
  if (i < EE) {
    int dst = bei[EE + i];
    int p = atomicAdd(&curb[dst], 1);
    listb[p] = bei[i];
    dlistb[p] = dst;
    elistb[p] = i;
  } else if (i < 2 * EE) {
    int e = i - EE;
    int dst = cei[EE + e];
    int p = atomicAdd(&curc[dst], 1);
    listc[p] = cei[e];
    dlistc[p] = dst;
    elistc[p] = e;
  }
}

// ---------------- encoder: relu(x@W_enc+b) -> bf16 (pre-BN), accumulate BN stats ----------------
__global__ void k_encoder_bf(const float* __restrict__ x, const float* __restrict__ W,
                             const float* __restrict__ b, ushort* __restrict__ hb,
                             float* __restrict__ sum, float* __restrict__ sumsq) {
  int t = threadIdx.x;
  int c = t & 127, r = t >> 7;
  int n0 = blockIdx.x * 64;
  float w0 = W[c], w1 = W[HH + c], w2 = W[2 * HH + c], bb = b[c];
  float ls = 0.f, lss = 0.f;
  for (int rr = r; rr < 64; rr += 2) {
    int n = n0 + rr;
    if (n < NN) {
      float v = fmaxf(x[n * 3] * w0 + x[n * 3 + 1] * w1 + x[n * 3 + 2] * w2 + bb, 0.f);
      ushort u = f2bf(v);
      hb[(size_t)n * HH + c] = u;
      float vr = bf2f(u);
      ls += vr; lss += vr * vr;
    }
  }
  __shared__ float red[2][HH];
  red[r][c] = ls; __syncthreads();
  if (r == 0) atomicAdd(&sum[c], red[0][c] + red[1][c]);
  __syncthreads();
  red[r][c] = lss; __syncthreads();
  if (r == 0) atomicAdd(&sumsq[c], red[0][c] + red[1][c]);
}

__global__ void k_bn_finalize(const float* __restrict__ sum, const float* __restrict__ sumsq,
                              const float* __restrict__ g, const float* __restrict__ be,
                              float* __restrict__ scale, float* __restrict__ shift, float invn) {
  int c = threadIdx.x;
  float m = sum[c] * invn;
  float v = fmaxf(sumsq[c] * invn - m * m, 0.f);
  float s = g[c] * rsqrtf(v + EPS_);
  scale[c] = s;
  shift[c] = be[c] - m * s;
}

// 2-relation finalize + BN-folded W2 (W2p = scale*W2, b2p = b2 + shift@W2)
__global__ void k_bn_finalize3(float* __restrict__ st, const float* __restrict__ g0,
                               const float* __restrict__ be0, const float* __restrict__ g1,
                               const float* __restrict__ be1,
                               const float* __restrict__ W2_0, const float* __restrict__ b2_0,
                               const float* __restrict__ W2_1, const float* __restrict__ b2_1,
                               float invn) {
  int t = threadIdx.x;  // 256
  int rel = t >> 7, c = t & 127;
  const float* sum = st + rel * 2 * HH;
  const float* sq  = sum + HH;
  float* scale = st + 512 + rel * 256;
  float* shift = scale + HH;
  const float* g = rel ? g1 : g0;
  const float* be = rel ? be1 : be0;
  const float* W2 = rel ? W2_1 : W2_0;
  float m = sum[c] * invn;
  float v = fmaxf(sq[c] * invn - m * m, 0.f);
  float sc = g[c] * rsqrtf(v + EPS_);
  float sh = be[c] - m * sc;
  scale[c] = sc;
  shift[c] = sh;
  float w20 = W2[c * 2], w21 = W2[c * 2 + 1];
  st[1024 + rel * 256 + c * 2 + 0] = sc * w20;
  st[1024 + rel * 256 + c * 2 + 1] = sc * w21;
  __shared__ float red[2][HH][2];
  red[rel][c][0] = sh * w20;
  red[rel][c][1] = sh * w21;
  __syncthreads();
  if (c < 2) {
    float s = 0.f;
    for (int i = 0; i < HH; ++i) s += red[rel][i][c];
    st[1536 + rel * 2 + c] = (rel ? b2_1 : b2_0)[c] + s;
  }
}

// ---------------- weight transposes to bf16 (merged) ----------------
__global__ void k_wt_all(const float* __restrict__ s0, const float* __restrict__ s1,
                         const float* __restrict__ s2, const float* __restrict__ s3,
                         ushort* __restrict__ d0, ushort* __restrict__ d1,
                         ushort* __restrict__ d2, ushort* __restrict__ d3,
                         const float* __restrict__ m0, const float* __restrict__ m1,
                         ushort* __restrict__ e0, ushort* __restrict__ e1) {
  int i = blockIdx.x * 256 + threadIdx.x;
  if (i < 4 * 16384) {
    int sel = i >> 14, loc = i & 16383;
    int k = loc >> 7, c = loc & 127;
    const float* s = sel == 0 ? s0 : sel == 1 ? s1 : sel == 2 ? s2 : s3;
    ushort* d = sel == 0 ? d0 : sel == 1 ? d1 : sel == 2 ? d2 : d3;
    d[c * 128 + k] = f2bf(s[loc]);
  } else if (i < 4 * 16384 + 2 * 32768) {
    int j = i - 4 * 16384;
    int sel = j >> 15, loc = j & 32767;
    int k = loc >> 7, c = loc & 127;
    const float* s = sel ? m1 : m0;
    ushort* d = sel ? e1 : e0;
    d[c * 256 + k] = f2bf(s[loc]);
  }
}

// ---------------- bf16 GEMM pair (optional fused BN on A-read) ----------------
template <int APPLYBN>
__global__ __launch_bounds__(256) void k_gemm_bf2(const ushort* __restrict__ X,
                                                  const ushort* __restrict__ Wt0,
                                                  ushort* __restrict__ Y0,
                                                  const ushort* __restrict__ Wt1,
                                                  ushort* __restrict__ Y1,
                                                  const float* __restrict__ bnsc,
                                                  const float* __restrict__ bnsh) {
  const int nb = gridDim.x >> 1;
  const int rel = blockIdx.x >= nb;
  const int blk = rel ? blockIdx.x - nb : blockIdx.x;
  const ushort* Wt = rel ? Wt1 : Wt0;
  ushort* Y = rel ? Y1 : Y0;
  const int t = threadIdx.x;
  const int l = t & 63, wid = t >> 6;
  const int wm = wid >> 1, wn = wid & 1;
  const int lr = l & 15, lg = l >> 4;
  const int n0 = blk * 64;
  f32x4 acc[2][4];
#pragma unroll
  for (int mf = 0; mf < 2; ++mf)
#pragma unroll
    for (int nf = 0; nf < 4; ++nf) acc[mf][nf] = (f32x4){0.f, 0.f, 0.f, 0.f};
  int r0 = n0 + wm * 32 + lr;
  int rA = min(r0, NN - 1), rB = min(r0 + 16, NN - 1);
  const ushort* xa = X + (size_t)rA * HH + lg * 8;
  const ushort* xb = X + (size_t)rB * HH + lg * 8;
#pragma unroll
  for (int ks = 0; ks < 4; ++ks) {
    bf16x8 a0 = *(const bf16x8*)(xa + ks * 32);
    bf16x8 a1 = *(const bf16x8*)(xb + ks * 32);
    if (APPLYBN) {
      int k0 = ks * 32 + lg * 8;
#pragma unroll
      for (int i = 0; i < 8; ++i) {
        float sc = bnsc[k0 + i], sh = bnsh[k0 + i];
        a0[i] = (short)f2bf(bf2f((ushort)a0[i]) * sc + sh);
        a1[i] = (short)f2bf(bf2f((ushort)a1[i]) * sc + sh);
      }
    }
#pragma unroll
    for (int nf = 0; nf < 4; ++nf) {
      int col = wn * 64 + nf * 16 + lr;
      bf16x8 b = *(const bf16x8*)(Wt + col * 128 + ks * 32 + lg * 8);
      acc[0][nf] = __builtin_amdgcn_mfma_f32_16x16x32_bf16(a0, b, acc[0][nf], 0, 0, 0);
      acc[1][nf] = __builtin_amdgcn_mfma_f32_16x16x32_bf16(a1, b, acc[1][nf], 0, 0, 0);
    }
  }
#pragma unroll
  for (int mf = 0; mf < 2; ++mf)
#pragma unroll
    for (int nf = 0; nf < 4; ++nf) {
      int col = wn * 64 + nf * 16 + lr;
#pragma unroll
      for (int j = 0; j < 4; ++j) {
        int row = n0 + wm * 32 + mf * 16 + lg * 4 + j;
        if (row < NN) Y[(size_t)row * HH + col] = f2bf(acc[mf][nf][j]);
      }
    }
}

// ---------------- UV GEMMs: U=h2@W1_top, V=h2@W1_bot per relation ----------------
__global__ __launch_bounds__(256) void k_gemm_uv(const ushort* __restrict__ X,
                                                 const ushort* __restrict__ Wm0,
                                                 const ushort* __restrict__ Wm1,
                                                 ushort* __restrict__ U0, ushort* __restrict__ V0,
                                                 ushort* __restrict__ U1, ushort* __restrict__ V1) {
  const int nb = gridDim.x >> 2;
  const int sel = blockIdx.x / nb;
  const int blk = blockIdx.x - sel * nb;
  const ushort* Wm = (sel >> 1) ? Wm1 : Wm0;
  const int koff = (sel & 1) * 128;
  ushort* Y = sel == 0 ? U0 : sel == 1 ? V0 : sel == 2 ? U1 : V1;
  const int t = threadIdx.x;
  const int l = t & 63, wid = t >> 6;
  const int wm = wid >> 1, wn = wid & 1;
  const int lr = l & 15, lg = l >> 4;
  const int n0 = blk * 64;
  f32x4 acc[2][4];
#pragma unroll
  for (int mf = 0; mf < 2; ++mf)
#pragma unroll
    for (int nf = 0; nf < 4; ++nf) acc[mf][nf] = (f32x4){0.f, 0.f, 0.f, 0.f};
  int r0 = n0 + wm * 32 + lr;
  int rA = min(r0, NN - 1), rB = min(r0 + 16, NN - 1);
  const ushort* xa = X + (size_t)rA * HH + lg * 8;
  const ushort* xb = X + (size_t)rB * HH + lg * 8;
#pragma unroll
  for (int ks = 0; ks < 4; ++ks) {
    bf16x8 a0 = *(const bf16x8*)(xa + ks * 32);
    bf16x8 a1 = *(const bf16x8*)(xb + ks * 32);
#pragma unroll
    for (int nf = 0; nf < 4; ++nf) {
      int col = wn * 64 + nf * 16 + lr;
      bf16x8 b = *(const bf16x8*)(Wm + col * 256 + koff + ks * 32 + lg * 8);
      acc[0][nf] = __builtin_amdgcn_mfma_f32_16x16x32_bf16(a0, b, acc[0][nf], 0, 0, 0);
      acc[1][nf] = __builtin_amdgcn_mfma_f32_16x16x32_bf16(a1, b, acc[1][nf], 0, 0, 0);
    }
  }
#pragma unroll
  for (int mf = 0; mf < 2; ++mf)
#pragma unroll
    for (int nf = 0; nf < 4; ++nf) {
      int col = wn * 64 + nf * 16 + lr;
#pragma unroll
      for (int j = 0; j < 4; ++j) {
        int row = n0 + wm * 32 + mf * 16 + lg * 4 + j;
        if (row < NN) Y[(size_t)row * HH + col] = f2bf(acc[mf][nf][j]);
      }
    }
}

// ---------------- fused aggregation v2: 16 nodes/block, 16 lanes x 8 cols, unroll-4 ----------------
template <int RELU>
__global__ __launch_bounds__(256) void k_agg2(
    const ushort* __restrict__ xwb, const ushort* __restrict__ xwc,
    const float* __restrict__ dinvb, const float* __restrict__ dinvc,
    const int* __restrict__ offb, const int* __restrict__ cntb,
    const int* __restrict__ listb,
    const int* __restrict__ offc, const int* __restrict__ cntc,
    const int* __restrict__ listc,
    const float* __restrict__ bb, const float* __restrict__ bc,
    ushort* __restrict__ out) {
  const int t = threadIdx.x;
  const int ln = t & 15;            // lane-within-node: cols ln*8 .. +7
  const int n = blockIdx.x * 16 + (t >> 4);
  if (n >= NN) return;
  const int c0 = ln * 8;
  float dnb = dinvb[n], dnc = dinvc[n];
  bf16x8 sb = *(const bf16x8*)(xwb + (size_t)n * HH + c0);
  bf16x8 sc = *(const bf16x8*)(xwc + (size_t)n * HH + c0);
  float acc[8];
#pragma unroll
  for (int i = 0; i < 8; ++i)
    acc[i] = bb[c0 + i] + bc[c0 + i] + dnb * dnb * bf2f((ushort)sb[i])
                                     + dnc * dnc * bf2f((ushort)sc[i]);
  // ---- relation b ----
  {
    int o = offb[n], e = o + cntb[n];
    float s[8];
#pragma unroll
    for (int i = 0; i < 8; ++i) s[i] = 0.f;
    for (; o + 4 <= e; o += 4) {
      int i0 = listb[o], i1 = listb[o + 1], i2 = listb[o + 2], i3 = listb[o + 3];
      float w0 = dinvb[i0], w1 = dinvb[i1], w2 = dinvb[i2], w3 = dinvb[i3];
      bf16x8 r0 = *(const bf16x8*)(xwb + (size_t)i0 * HH + c0);
      bf16x8 r1 = *(const bf16x8*)(xwb + (size_t)i1 * HH + c0);
      bf16x8 r2 = *(const bf16x8*)(xwb + (size_t)i2 * HH + c0);
      bf16x8 r3 = *(const bf16x8*)(xwb + (size_t)i3 * HH + c0);
#pragma unroll
      for (int i = 0; i < 8; ++i)
        s[i] += w0 * bf2f((ushort)r0[i]) + w1 * bf2f((ushort)r1[i])
              + w2 * bf2f((ushort)r2[i]) + w3 * bf2f((ushort)r3[i]);
    }
    for (; o < e; ++o) {
      int src = listb[o];
      float w = dinvb[src];
      bf16x8 r = *(const bf16x8*)(xwb + (size_t)src * HH + c0);
#pragma unroll
      for (int i = 0; i < 8; ++i) s[i] += w * bf2f((ushort)r[i]);
    }
#pragma unroll
    for (int i = 0; i < 8; ++i) acc[i] += dnb * s[i];
  }
  // ---- relation c ----
  {
    int o = offc[n], e = o + cntc[n];
    float s[8];
#pragma unroll
    for (int i = 0; i < 8; ++i) s[i] = 0.f;
    for (; o + 4 <= e; o += 4) {
      int i0 = listc[o], i1 = listc[o + 1], i2 = listc[o + 2], i3 = listc[o + 3];
      float w0 = dinvc[i0], w1 = dinvc[i1], w2 = dinvc[i2], w3 = dinvc[i3];
      bf16x8 r0 = *(const bf16x8*)(xwc + (size_t)i0 * HH + c0);
      bf16x8 r1 = *(const bf16x8*)(xwc + (size_t)i1 * HH + c0);
      bf16x8 r2 = *(const bf16x8*)(xwc + (size_t)i2 * HH + c0);
      bf16x8 r3 = *(const bf16x8*)(xwc + (size_t)i3 * HH + c0);
#pragma unroll
      for (int i = 0; i < 8; ++i)
        s[i] += w0 * bf2f((ushort)r0[i]) + w1 * bf2f((ushort)r1[i])
              + w2 * bf2f((ushort)r2[i]) + w3 * bf2f((ushort)r3[i]);
    }
    for (; o < e; ++o) {
      int src = listc[o];
      float w = dinvc[src];
      bf16x8 r = *(const bf16x8*)(xwc + (size_t)src * HH + c0);
#pragma unroll
      for (int i = 0; i < 8; ++i) s[i] += w * bf2f((ushort)r[i]);
    }
#pragma unroll
    for (int i = 0; i < 8; ++i) acc[i] += dnc * s[i];
  }
  bf16x8 ov;
#pragma unroll
  for (int i = 0; i < 8; ++i) {
    float v = RELU ? fmaxf(acc[i], 0.f) : acc[i];
    ov[i] = (short)f2bf(v);
  }
  *(bf16x8*)(out + (size_t)n * HH + c0) = ov;
}

// ---------------- edge pass 1 (edge-centric, 2-edge ILP): stats of relu(U[s]+V[d]+b1) ----------------
// 256 threads = 32 edge slots x 8 col-groups of 16; each thread handles edges p and p+32
// per grid-stride iteration (8 independent 16B gathers in flight).
__global__ __launch_bounds__(256) void k_edge_pass1e(
    const ushort* __restrict__ U0, const ushort* __restrict__ V0,
    const ushort* __restrict__ U1, const ushort* __restrict__ V1,
    const int* __restrict__ sl0, const int* __restrict__ dl0,
    const int* __restrict__ sl1, const int* __restrict__ dl1,
    const float* __restrict__ b1_0, const float* __restrict__ b1_1,
    float* __restrict__ st) {
  const int nbk = gridDim.x >> 1;
  const int rel = blockIdx.x >= nbk;
  const int blk = rel ? blockIdx.x - nbk : blockIdx.x;
  const ushort* U = rel ? U1 : U0;
  const ushort* V = rel ? V1 : V0;
  const int* sl = rel ? sl1 : sl0;
  const int* dl = rel ? dl1 : dl0;
  const float* b1 = rel ? b1_1 : b1_0;

  __shared__ float b1s[HH], redA[HH], redB[HH];
  const int t = threadIdx.x;
  if (t < HH) { b1s[t] = b1[t]; redA[t] = 0.f; redB[t] = 0.f; }
  __syncthreads();
  const int cg = t & 7, el = t >> 3;
  const int c0 = cg * 16;

  float ls[16], lss[16];
#pragma unroll
  for (int i = 0; i < 16; ++i) { ls[i] = 0.f; lss[i] = 0.f; }

  for (int p0 = blk * 64; p0 < EE; p0 += nbk * 64) {
    int pA = p0 + el, pB = p0 + 32 + el;
    if (pB < EE) {  // common path: both edges valid
      int sA = sl[pA], dA = dl[pA], sB = sl[pB], dB = dl[pB];
      bf16x8 uA0 = *(const bf16x8*)(U + (size_t)sA * HH + c0);
      bf16x8 uA1 = *(const bf16x8*)(U + (size_t)sA * HH + c0 + 8);
      bf16x8 vA0 = *(const bf16x8*)(V + (size_t)dA * HH + c0);
      bf16x8 vA1 = *(const bf16x8*)(V + (size_t)dA * HH + c0 + 8);
      bf16x8 uB0 = *(const bf16x8*)(U + (size_t)sB * HH + c0);
      bf16x8 uB1 = *(const bf16x8*)(U + (size_t)sB * HH + c0 + 8);
      bf16x8 vB0 = *(const bf16x8*)(V + (size_t)dB * HH + c0);
      bf16x8 vB1 = *(const bf16x8*)(V + (size_t)dB * HH + c0 + 8);
#pragma unroll
      for (int i = 0; i < 8; ++i) {
        float rA = fmaxf(bf2f((ushort)uA0[i]) + bf2f((ushort)vA0[i]) + b1s[c0 + i], 0.f);
        float rB = fmaxf(bf2f((ushort)uB0[i]) + bf2f((ushort)vB0[i]) + b1s[c0 + i], 0.f);
        ls[i] += rA + rB; lss[i] += rA * rA + rB * rB;
        float rA2 = fmaxf(bf2f((ushort)uA1[i]) + bf2f((ushort)vA1[i]) + b1s[c0 + 8 + i], 0.f);
        float rB2 = fmaxf(bf2f((ushort)uB1[i]) + bf2f((ushort)vB1[i]) + b1s[c0 + 8 + i], 0.f);
        ls[8 + i] += rA2 + rB2; lss[8 + i] += rA2 * rA2 + rB2 * rB2;
      }
    } else if (pA < EE) {  // tail: only edge A valid
      int sA = sl[pA], dA = dl[pA];
      bf16x8 uA0 = *(const bf16x8*)(U + (size_t)sA * HH + c0);
      bf16x8 uA1 = *(const bf16x8*)(U + (size_t)sA * HH + c0 + 8);
      bf16x8 vA0 = *(const bf16x8*)(V + (size_t)dA * HH + c0);
      bf16x8 vA1 = *(const bf16x8*)(V + (size_t)dA * HH + c0 + 8);
#pragma unroll
      for (int i = 0; i < 8; ++i) {
        float rA = fmaxf(bf2f((ushort)uA0[i]) + bf2f((ushort)vA0[i]) + b1s[c0 + i], 0.f);
        ls[i] += rA; lss[i] += rA * rA;
        float rA2 = fmaxf(bf2f((ushort)uA1[i]) + bf2f((ushort)vA1[i]) + b1s[c0 + 8 + i], 0.f);
        ls[8 + i] += rA2; lss[8 + i] += rA2 * rA2;
      }
    }
  }
  // reduce over the wave's 8 edge slots (lane bits 3,4,5)
#pragma unroll
  for (int m = 8; m <= 32; m <<= 1)
#pragma unroll
    for (int i = 0; i < 16; ++i) {
      ls[i] += __shfl_xor(ls[i], m, 64);
      lss[i] += __shfl_xor(lss[i], m, 64);
    }
  if ((t & 63) < 8) {
#pragma unroll
    for (int i = 0; i < 16; ++i) {
      atomicAdd(&redA[c0 + i], ls[i]);
      atomicAdd(&redB[c0 + i], lss[i]);
    }
  }
  __syncthreads();
  if (t < HH) {
    atomicAdd(&st[rel * 2 * HH + t], redA[t]);
    atomicAdd(&st[rel * 2 * HH + HH + t], redB[t]);
  }
}

// ---------------- edge pass 2 (edge-centric, 2-edge ILP): out = relu(U[s]+V[d]+b1) @ W2p + b2p ----------------
__global__ __launch_bounds__(256) void k_edge_pass2e(
    const ushort* __restrict__ U0, const ushort* __restrict__ V0,
    const ushort* __restrict__ U1, const ushort* __restrict__ V1,
    const int* __restrict__ sl0, const int* __restrict__ dl0, const int* __restrict__ el0,
    const int* __restrict__ sl1, const int* __restrict__ dl1, const int* __restrict__ el1,
    const float* __restrict__ b1_0, const float* __restrict__ b1_1,
    const float* __restrict__ st, float* __restrict__ out) {
  const int nbk = gridDim.x >> 1;
  const int rel = blockIdx.x >= nbk;
  const int blk = rel ? blockIdx.x - nbk : blockIdx.x;
  const ushort* U = rel ? U1 : U0;
  const ushort* V = rel ? V1 : V0;
  const int* sl = rel ? sl1 : sl0;
  const int* dl = rel ? dl1 : dl0;
  const int* el = rel ? el1 : el0;
  const float* b1 = rel ? b1_1 : b1_0;
  float* o_ = out + (size_t)rel * 2 * EE;

  __shared__ float b1s[HH], w2s[256], b2s[2];
  const int t = threadIdx.x;
  if (t < HH) b1s[t] = b1[t];
  w2s[t] = st[1024 + rel * 256 + t];
  if (t < 2) b2s[t] = st[1536 + rel * 2 + t];
  __syncthreads();
  const int cg = t & 7, es = t >> 3;
  const int c0 = cg * 16;

  int pA = blk * 64 + es;
  int pB = pA + 32;
  bool okA = pA < EE, okB = pB < EE;
  int sA = okA ? sl[pA] : 0, dA = okA ? dl[pA] : 0;
  int sB = okB ? sl[pB] : 0, dB = okB ? dl[pB] : 0;

  bf16x8 uA0 = *(const bf16x8*)(U + (size_t)sA * HH + c0);
  bf16x8 uA1 = *(const bf16x8*)(U + (size_t)sA * HH + c0 + 8);
  bf16x8 vA0 = *(const bf16x8*)(V + (size_t)dA * HH + c0);
  bf16x8 vA1 = *(const bf16x8*)(V + (size_t)dA * HH + c0 + 8);
  bf16x8 uB0 = *(const bf16x8*)(U + (size_t)sB * HH + c0);
  bf16x8 uB1 = *(const bf16x8*)(U + (size_t)sB * HH + c0 + 8);
  bf16x8 vB0 = *(const bf16x8*)(V + (size_t)dB * HH + c0);
  bf16x8 vB1 = *(const bf16x8*)(V + (size_t)dB * HH + c0 + 8);

  float pa0 = 0.f, pa1 = 0.f, pb0 = 0.f, pb1 = 0.f;
#pragma unroll
  for (int i = 0; i < 8; ++i) {
    float wa = w2s[(c0 + i) * 2], wb = w2s[(c0 + i) * 2 + 1];
    float rA = fmaxf(bf2f((ushort)uA0[i]) + bf2f((ushort)vA0[i]) + b1s[c0 + i], 0.f);
    pa0 += rA * wa; pa1 += rA * wb;
    float rB = fmaxf(bf2f((ushort)uB0[i]) + bf2f((ushort)vB0[i]) + b1s[c0 + i], 0.f);
    pb0 += rB * wa; pb1 += rB * wb;
    float wa2 = w2s[(c0 + 8 + i) * 2], wb2 = w2s[(c0 + 8 + i) * 2 + 1];
    float rA2 = fmaxf(bf2f((ushort)uA1[i]) + bf2f((ushort)vA1[i]) + b1s[c0 + 8 + i], 0.f);
    pa0 += rA2 * wa2; pa1 += rA2 * wb2;
    float rB2 = fmaxf(bf2f((ushort)uB1[i]) + bf2f((ushort)vB1[i]) + b1s[c0 + 8 + i], 0.f);
    pb0 += rB2 * wa2; pb1 += rB2 * wb2;
  }
  // reduce across the 8 col-groups of each edge (lane bits 0..2)
#pragma unroll
  for (int m = 4; m >= 1; m >>= 1) {
    pa0 += __shfl_xor(pa0, m, 64); pa1 += __shfl_xor(pa1, m, 64);
    pb0 += __shfl_xor(pb0, m, 64); pb1 += __shfl_xor(pb1, m, 64);
  }
  if (cg == 0) {
    float b20 = b2s[0], b21 = b2s[1];
    if (okA) {
      int eid = el[pA];
      o_[(size_t)eid * 2 + 0] = pa0 + b20;
      o_[(size_t)eid * 2 + 1] = pa1 + b21;
    }
    if (okB) {
      int eid = el[pB];
      o_[(size_t)eid * 2 + 0] = pb0 + b20;
      o_[(size_t)eid * 2 + 1] = pb1 + b21;
    }
  }
}

// ---------------- edge types ----------------
__global__ void k_edge_types(float* __restrict__ out) {
  int i = blockIdx.x * 256 + threadIdx.x;
  if (i < 2 * EE) out[(size_t)2 * EE * 2 + i] = (i < EE) ? 0.0f : 1.0f;
}

extern "C" void kernel_launch(void* const* d_in, const int* in_sizes, int n_in,
                              void* d_out, int out_size, void* d_ws, size_t ws_size,
                              hipStream_t stream) {
  const float* x      = (const float*)d_in[0];
  const int*   bei    = (const int*)d_in[1];
  const int*   cei    = (const int*)d_in[2];
  const float* W_enc  = (const float*)d_in[3];
  const float* b_enc  = (const float*)d_in[4];
  const float* g_enc  = (const float*)d_in[5];
  const float* be_enc = (const float*)d_in[6];
  const float* W1b = (const float*)d_in[7];  const float* b1b = (const float*)d_in[8];
  const float* W1c = (const float*)d_in[9];  const float* b1c = (const float*)d_in[10];
  const float* W2b = (const float*)d_in[11]; const float* b2b = (const float*)d_in[12];
  const float* W2c = (const float*)d_in[13]; const float* b2c = (const float*)d_in[14];
  const float* Wbp1 = (const float*)d_in[15]; const float* bbp1 = (const float*)d_in[16];
  const float* gbp  = (const float*)d_in[17]; const float* bebp = (const float*)d_in[18];
  const float* Wbp2 = (const float*)d_in[19]; const float* bbp2 = (const float*)d_in[20];
  const float* Wcp1 = (const float*)d_in[21]; const float* bcp1 = (const float*)d_in[22];
  const float* gcp  = (const float*)d_in[23]; const float* becp = (const float*)d_in[24];
  const float* Wcp2 = (const float*)d_in[25]; const float* bcp2 = (const float*)d_in[26];
  float* out = (float*)d_out;

  // ---- workspace layout (~74 MB) ----
  ushort* hb   = (ushort*)d_ws;                 // h (bf16, pre-BN); later h2  [N*H]
  ushort* h1b  = hb + (size_t)NN * HH;          // h1; later Uc
  ushort* xwb  = h1b + (size_t)NN * HH;         // xw tmp; later Ub
  ushort* xwc  = xwb + (size_t)NN * HH;         // xw tmp; later Vb
  ushort* vcb  = xwc + (size_t)NN * HH;         // Vc
  ushort* Wt1b = vcb + (size_t)NN * HH;         // 128x128 transposed weights (bf16)
  ushort* Wt1c = Wt1b + 128 * 128;
  ushort* Wt2b = Wt1c + 128 * 128;
  ushort* Wt2c = Wt2b + 128 * 128;
  ushort* Wmb  = Wt2c + 128 * 128;              // MLP W1^T [128][256]
  ushort* Wmc  = Wmb + 256 * 128;
  float* dinv  = (float*)(Wmc + 256 * 128);
  float* dinvb = dinv, *dinvc = dinv + NN;
  float* st    = dinvc + NN;                    // 2048 floats (see layout above)
  int* cnt  = (int*)(st + 2048);
  int* cntb = cnt, *cntc = cnt + NN;
  int* offb = cntc + NN; int* offc = offb + NN;
  int* curb = offc + NN; int* curc = curb + NN;
  int* part = curc + NN;
  int* listb  = part + 2 * SCB;
  int* listc  = listb + EE;
  int* dlistb = listc + EE;
  int* dlistc = dlistb + EE;
  int* elistb = dlistc + EE;
  int* elistc = elistb + EE;

  // ---- degrees + CSR ----
  hipMemsetAsync(cnt, 0, sizeof(int) * 2 * NN, stream);
  hipMemsetAsync(st, 0, sizeof(float) * 2 * HH, stream);
  k_count<<<(2 * EE + 255) / 256, 256, 0, stream>>>(bei, cei, cntb, cntc);
  k_dinv<<<(2 * NN + 255) / 256, 256, 0, stream>>>(cnt, dinv);
  k_scan_part<<<2 * SCB, 256, 0, stream>>>(cnt, part);
  k_scan_base<<<1, 256, 0, stream>>>(part);
  k_scan_off<<<2 * SCB, 256, 0, stream>>>(cnt, part, offb, curb);
  k_fill<<<(2 * EE + 255) / 256, 256, 0, stream>>>(bei, cei, curb, listb, dlistb, elistb,
                                                   curc, listc, dlistc, elistc);

  // ---- encoder + BN (apply fused into layer-1 GEMM) ----
  k_encoder_bf<<<(NN + 63) / 64, 256, 0, stream>>>(x, W_enc, b_enc, hb, st, st + HH);
  k_bn_finalize<<<1, 128, 0, stream>>>(st, st + HH, g_enc, be_enc, st + 512, st + 640, 1.0f / NN);

  // ---- weight transposes (merged) ----
  k_wt_all<<<(4 * 16384 + 2 * 32768 + 255) / 256, 256, 0, stream>>>(
      W1b, W1c, W2b, W2c, Wt1b, Wt1c, Wt2b, Wt2c, Wbp1, Wcp1, Wmb, Wmc);

  int gblk = (NN + 63) / 64;
  int a2blk = (NN + 15) / 16;
  // ---- GCN layer 1 (BN applied on A-read) ----
  k_gemm_bf2<1><<<2 * gblk, 256, 0, stream>>>(hb, Wt1b, xwb, Wt1c, xwc, st + 512, st + 640);
  k_agg2<1><<<a2blk, 256, 0, stream>>>(xwb, xwc, dinvb, dinvc, offb, cntb, listb,
                                       offc, cntc, listc, b1b, b1c, h1b);
  // ---- GCN layer 2 ----
  k_gemm_bf2<0><<<2 * gblk, 256, 0, stream>>>(h1b, Wt2b, xwb, Wt2c, xwc, nullptr, nullptr);
  k_agg2<0><<<a2blk, 256, 0, stream>>>(xwb, xwc, dinvb, dinvc, offb, cntb, listb,
                                       offc, cntc, listc, b2b, b2c, hb);

  // ---- edge predictors: factored concat-GEMM ----
  ushort* Ub = xwb;  ushort* Vb = xwc;   // xw buffers dead after layer-2 agg
  ushort* Uc = h1b;  ushort* Vc = vcb;   // h1 dead after layer-2 gemm
  k_gemm_uv<<<4 * gblk, 256, 0, stream>>>(hb, Wmb, Wmc, Ub, Vb, Uc, Vc);

  hipMemsetAsync(st, 0, sizeof(float) * 4 * HH, stream);
  int p1b = 1024;                                   // grid-stride blocks per relation
  k_edge_pass1e<<<2 * p1b, 256, 0, stream>>>(Ub, Vb, Uc, Vc, listb, dlistb, listc, dlistc,
                                             bbp1, bcp1, st);
  k_bn_finalize3<<<1, 256, 0, stream>>>(st, gbp, bebp, gcp, becp,
                                        Wbp2, bbp2, Wcp2, bcp2, 1.0f / EE);
  int p2b = (EE + 63) / 64;
  k_edge_pass2e<<<2 * p2b, 256, 0, stream>>>(Ub, Vb, Uc, Vc,
                                             listb, dlistb, elistb, listc, dlistc, elistc,
                                             bbp1, bcp1, st, out);

  k_edge_types<<<(2 * EE + 255) / 256, 256, 0, stream>>>(out);
}